// Round 12
// baseline (1319.550 us; speedup 1.0000x reference)
//
#include <hip/hip_runtime.h>
#include <hip/hip_bf16.h>

// Pipeline (7 launches + 1 memset):
//  k_pool   : x -> pooled xp + group partials [+ fused wconv] [+ fused stats tail:
//             last block (atomic counter) reduces partials -> gstats]
//  k_xr     : xr = GN_affine(xp) + posenc -> bf16 (512,4096)
//  k_gemmP  : qkv = Wq(1536,512) x xr -> fragment-ordered qtg/ktg/vtg directly
//  k_attn   : flash attn, m==0 softmax, lane-local l, 64-key tiles, dbuf LDS,
//             counted vmcnt, 4 segments (grid 1024 = 4 blocks/CU)
//  k_merge  : sum 4 seg partials -> attn_bT (n-major) bf16
//  k_gemmT  : low = Wp(512,512) x attn_bT^T, 64-row tiles (grid 256)
//  k_up     : out = x + gamma*(bilerp_4x(low)+proj_b); NT x-load, shfl neighbors,
//             NT store

typedef __attribute__((ext_vector_type(4))) short short4v;
typedef __attribute__((ext_vector_type(8))) short short8v;
typedef __attribute__((ext_vector_type(4))) float f32x4;
typedef __attribute__((ext_vector_type(4))) unsigned int u32x4;

#define MFMA16(a, b, c) __builtin_amdgcn_mfma_f32_16x16x32_bf16(a, b, c, 0, 0, 0)

__device__ __forceinline__ unsigned short bf16r(float f) {
    unsigned int u = __builtin_bit_cast(unsigned int, f);
    u += 0x7fffu + ((u >> 16) & 1u);
    return (unsigned short)(u >> 16);
}
__device__ __forceinline__ float bff(unsigned short s) {
    unsigned int u = ((unsigned int)s) << 16;
    return __builtin_bit_cast(float, u);
}
__device__ __forceinline__ unsigned int fbits(float f) {
    return __builtin_bit_cast(unsigned int, f);
}

typedef const __attribute__((address_space(1))) unsigned int guint;
typedef __attribute__((address_space(3))) unsigned int luint;
__device__ __forceinline__ void gload16(const void* g, void* l) {
    __builtin_amdgcn_global_load_lds((guint*)g, (luint*)l, 16, 0, 0);
}

// ---------------- pool + partials (+ wconv) + fused stats tail ----------------
__global__ __launch_bounds__(256) void k_pool(const float* __restrict__ x,
                                              float* __restrict__ xp,
                                              float* __restrict__ partials,
                                              const float* __restrict__ qkv_w,
                                              const float* __restrict__ proj_w,
                                              const float* __restrict__ temp,
                                              unsigned short* __restrict__ wq_b,
                                              unsigned short* __restrict__ wp_b,
                                              int* __restrict__ cnt,
                                              float* __restrict__ gstats) {
    int t = threadIdx.x;
    if (blockIdx.x >= 64) {
        int idx = ((blockIdx.x - 64) * 512 + blockIdx.y) * 256 + t;
        const int NQ = 1536 * 512;
        const int NTOT = NQ + 512 * 512;
        if (idx < NQ) {
            int o = idx >> 9;
            float sc = (o < 512) ? temp[o >> 6] * 0.125f * 1.44269504f : 1.0f;
            wq_b[idx] = bf16r(qkv_w[idx] * sc);
        } else if (idx < NTOT) {
            wp_b[idx - NQ] = bf16r(proj_w[idx - NQ]);
        }
        return;
    }
    int hr = blockIdx.x;
    int c  = blockIdx.y;
    int r = t >> 6, wq = t & 63;
    const f32x4* src = (const f32x4*)(x + (size_t)c * 65536 + (size_t)(4 * hr + r) * 256 + 4 * wq);
    f32x4 v = __builtin_nontemporal_load(src);
    float s4 = v[0] + v[1] + v[2] + v[3];
    float q4 = v[0] * v[0] + v[1] * v[1] + v[2] * v[2] + v[3] * v[3];

    __shared__ float sm[256];
    __shared__ float wq4[4];
    __shared__ int lastFlag;
    sm[t] = s4;
    float qq = q4;
#pragma unroll
    for (int off = 1; off < 64; off <<= 1) qq += __shfl_xor(qq, off, 64);
    if ((t & 63) == 0) wq4[t >> 6] = qq;
    __syncthreads();
    if (t < 64) {
        float cs = sm[t] + sm[64 + t] + sm[128 + t] + sm[192 + t];
        xp[(size_t)c * 4096 + hr * 64 + t] = cs * (1.0f / 16.0f);
        float ts = cs;
#pragma unroll
        for (int off = 1; off < 64; off <<= 1) ts += __shfl_xor(ts, off, 64);
        if (t == 0) {
            int g = c >> 6;
            int slot = (c & 63) * 64 + hr;
            partials[(size_t)(g * 4096 + slot) * 2 + 0] = ts;
            partials[(size_t)(g * 4096 + slot) * 2 + 1] = wq4[0] + wq4[1] + wq4[2] + wq4[3];
        }
    }
    // fused stats tail: last pool block reduces partials -> gstats
    if (t == 0) {
        __threadfence();
        int old = atomicAdd(cnt, 1);
        lastFlag = (old == 64 * 512 - 1);
    }
    __syncthreads();
    if (!lastFlag) return;

    __shared__ float ss[4], qs[4];
    for (int g = 0; g < 8; g++) {
        float s = 0.f, q = 0.f;
        for (int i = t; i < 4096; i += 256) {
            s += partials[(size_t)(g * 4096 + i) * 2 + 0];
            q += partials[(size_t)(g * 4096 + i) * 2 + 1];
        }
#pragma unroll
        for (int off = 1; off < 64; off <<= 1) {
            s += __shfl_xor(s, off, 64);
            q += __shfl_xor(q, off, 64);
        }
        if ((t & 63) == 0) { ss[t >> 6] = s; qs[t >> 6] = q; }
        __syncthreads();
        if (t == 0) {
            float S = ss[0] + ss[1] + ss[2] + ss[3];
            float Q = qs[0] + qs[1] + qs[2] + qs[3];
            const float inv = 1.0f / 4194304.0f;
            float m = S * inv;
            float var = Q * inv - m * m;
            gstats[2 * g] = m;
            gstats[2 * g + 1] = rsqrtf(var + 1e-5f);
        }
        __syncthreads();
    }
}

// ---------------- GN affine + positional encoding -> bf16 ----------------
__global__ __launch_bounds__(256) void k_xr(const float* __restrict__ xp,
                                            const float* __restrict__ gs,
                                            const float* __restrict__ gw,
                                            const float* __restrict__ gb,
                                            unsigned short* __restrict__ xr) {
    int idx = blockIdx.x * 256 + threadIdx.x;
    int c = idx >> 12, n = idx & 4095;
    int hr = n >> 6, wr = n & 63;
    int g = c >> 6;
    float m = gs[2 * g], rs = gs[2 * g + 1];
    float xn = (xp[idx] - m) * rs * gw[c] + gb[c];
    int i = c >> 2, kind = c & 3;
    float di = expf(-(float)i * 0.07195578415606394f);
    float arg = ((kind < 2) ? (float)hr : (float)wr) * di;
    float pe = 0.01f * ((kind & 1) ? cosf(arg) : sinf(arg));
    xr[idx] = bf16r(xn + pe);
}

// ---------------- QKV GEMM with fused fragment-order epilogue ----------------
__global__ __launch_bounds__(256) void k_gemmP(const unsigned short* __restrict__ A,
                                               const unsigned short* __restrict__ B,
                                               unsigned short* __restrict__ qtg,
                                               unsigned short* __restrict__ ktg,
                                               unsigned short* __restrict__ vtg) {
    __shared__ __align__(16) char smem[33792];
    unsigned short (*As)[36] = (unsigned short(*)[36])smem;
    unsigned short (*Bs)[36] = (unsigned short(*)[36])(smem + 9216);
    unsigned short (*ct)[132] = (unsigned short(*)[132])smem;  // epilogue reuse

    int t = threadIdx.x;
    int w = t >> 6, l = t & 63, l15 = l & 15, lg = l >> 4;
    int wrow = w >> 1, wcol = w & 1;
    int m0 = blockIdx.y * 128, n0 = blockIdx.x * 128;
    f32x4 acc[4][4] = {};

    for (int k0 = 0; k0 < 512; k0 += 32) {
#pragma unroll
        for (int i = 0; i < 4; i++) {
            int idx = t + 256 * i;
            int row = idx >> 3, kc = idx & 7;
            short4v av = *(const short4v*)(A + (size_t)(m0 + row) * 512 + k0 + 4 * kc);
            *(short4v*)&As[row][4 * kc] = av;
        }
#pragma unroll
        for (int i = 0; i < 4; i++) {
            int idx = t + 256 * i;
            int kr = idx >> 5, nc = idx & 31;
            short4v bv = *(const short4v*)(B + (size_t)(k0 + kr) * 4096 + n0 + 4 * nc);
#pragma unroll
            for (int j = 0; j < 4; j++) Bs[4 * nc + j][kr] = (unsigned short)bv[j];
        }
        __syncthreads();

        short8v af[4];
#pragma unroll
        for (int mi = 0; mi < 4; mi++) {
            int ar = wrow * 64 + mi * 16 + l15;
            short4v a0 = *(const short4v*)&As[ar][4 * lg];
            short4v a1 = *(const short4v*)&As[ar][16 + 4 * lg];
            af[mi] = __builtin_shufflevector(a0, a1, 0, 1, 2, 3, 4, 5, 6, 7);
        }
#pragma unroll
        for (int ni = 0; ni < 4; ni++) {
            int bc = wcol * 64 + ni * 16 + l15;
            short4v b0 = *(const short4v*)&Bs[bc][4 * lg];
            short4v b1 = *(const short4v*)&Bs[bc][16 + 4 * lg];
            short8v bf = __builtin_shufflevector(b0, b1, 0, 1, 2, 3, 4, 5, 6, 7);
#pragma unroll
            for (int mi = 0; mi < 4; mi++) acc[mi][ni] = MFMA16(af[mi], bf, acc[mi][ni]);
        }
        __syncthreads();
    }

#pragma unroll
    for (int mi = 0; mi < 4; mi++)
#pragma unroll
        for (int ni = 0; ni < 4; ni++) {
            int ml = wrow * 64 + mi * 16 + 4 * lg;
            int nl = wcol * 64 + ni * 16 + l15;
#pragma unroll
            for (int r = 0; r < 4; r++) ct[ml + r][nl] = bf16r(acc[mi][ni][r]);
        }
    __syncthreads();

    int y = blockIdx.y;
#pragma unroll
    for (int i = 0; i < 8; i++) {
        int gc = t + 256 * i;  // [0, 2048)
        int hg = gc >> 10, rem = gc & 1023;
        unsigned short o[8];
        unsigned short* dst;
        if (y < 4) {  // Q
            int nu_loc = rem >> 8, cidx = rem & 255;
            int s = cidx >> 7, lgc = (cidx >> 5) & 3, col = cidx & 31;
#pragma unroll
            for (int j = 0; j < 4; j++) {
                o[j] = ct[hg * 64 + s * 32 + 4 * lgc + j][nu_loc * 32 + col];
                o[4 + j] = ct[hg * 64 + s * 32 + 16 + 4 * lgc + j][nu_loc * 32 + col];
            }
            int h = y * 2 + hg;
            dst = qtg + ((size_t)(h * 128 + (n0 >> 5) + nu_loc)) * 2048 + cidx * 8;
        } else if (y < 8) {  // K
            int Tloc = rem >> 9, cidx = rem & 511;
            int s = cidx >> 8, lgc = (cidx >> 6) & 3, m64 = cidx & 63;
#pragma unroll
            for (int j = 0; j < 4; j++) {
                o[j] = ct[hg * 64 + s * 32 + 4 * lgc + j][Tloc * 64 + m64];
                o[4 + j] = ct[hg * 64 + s * 32 + 16 + 4 * lgc + j][Tloc * 64 + m64];
            }
            int h = (y - 4) * 2 + hg;
            dst = ktg + ((size_t)(h * 64 + (n0 >> 6) + Tloc)) * 4096 + cidx * 8;
        } else {  // V
            int Tloc = rem >> 9, cidx = rem & 511;
            int mh = cidx >> 8, lgc = (cidx >> 6) & 3, d = cidx & 63;
#pragma unroll
            for (int j = 0; j < 4; j++) {
                o[j] = ct[hg * 64 + d][Tloc * 64 + mh * 32 + 4 * lgc + j];
                o[4 + j] = ct[hg * 64 + d][Tloc * 64 + mh * 32 + 16 + 4 * lgc + j];
            }
            int h = (y - 8) * 2 + hg;
            dst = vtg + ((size_t)(h * 64 + (n0 >> 6) + Tloc)) * 4096 + cidx * 8;
        }
        *(short8v*)dst = *(const short8v*)o;
    }
}

// ---------------- flash attention: 4 segs, dbuf, counted vmcnt ----------------
__global__ __launch_bounds__(256, 5) void k_attn(const unsigned short* __restrict__ qtg,
                                                 const unsigned short* __restrict__ ktg,
                                                 const unsigned short* __restrict__ vtg,
                                                 unsigned short* __restrict__ opart,
                                                 float* __restrict__ lgl) {
    __shared__ __align__(16) unsigned short kbuf[2][4096];
    __shared__ __align__(16) unsigned short vbuf[2][4096];
    int t = threadIdx.x;
    int l = t & 63, l15 = l & 15, lg = l >> 4, w = t >> 6;
    int qt = blockIdx.x, h = blockIdx.y, seg = blockIdx.z;
    int nu = qt * 4 + w;

    const unsigned short* qb = qtg + ((size_t)(h * 128 + nu)) * 2048;
    const unsigned short* kb = ktg + ((size_t)(h * 64 + seg * 16)) * 4096;
    const unsigned short* vb = vtg + ((size_t)(h * 64 + seg * 16)) * 4096;

    short8v qf[2][2];
#pragma unroll
    for (int ng = 0; ng < 2; ng++)
#pragma unroll
        for (int s = 0; s < 2; s++)
            qf[ng][s] = *(const short8v*)(qb + ((s * 4 + lg) * 32 + ng * 16 + l15) * 8);

    f32x4 od[2][4] = {};
    float lsum[2] = {0.f, 0.f};

#define STAGE(kt, b)                                                            \
    {                                                                           \
        gload16(kb + (size_t)(kt) * 4096 + t * 8, &kbuf[b][t * 8]);             \
        gload16(kb + (size_t)(kt) * 4096 + (t + 256) * 8, &kbuf[b][(t + 256) * 8]); \
        gload16(vb + (size_t)(kt) * 4096 + t * 8, &vbuf[b][t * 8]);             \
        gload16(vb + (size_t)(kt) * 4096 + (t + 256) * 8, &vbuf[b][(t + 256) * 8]); \
    }

    STAGE(0, 0);

    int u = 0;
#pragma unroll 1
    for (int j = 0; j < 16; j++) {
        if (j < 15) {
            STAGE(j + 1, u ^ 1);
            asm volatile("s_waitcnt vmcnt(4)" ::: "memory");
        } else {
            asm volatile("s_waitcnt vmcnt(0)" ::: "memory");
        }
        __builtin_amdgcn_s_barrier();
        __builtin_amdgcn_sched_barrier(0);

        const unsigned short* kl = &kbuf[u][0];
        const unsigned short* vl = &vbuf[u][0];

        u32x4 pwA, pwB;
        short8v pb[2][2];
#pragma unroll
        for (int mf = 0; mf < 4; mf++) {
            short8v k0 = *(const short8v*)(kl + ((0 + lg) * 64 + mf * 16 + l15) * 8);
            short8v k1 = *(const short8v*)(kl + ((4 + lg) * 64 + mf * 16 + l15) * 8);
            f32x4 s0 = {}, s1 = {};
            __builtin_amdgcn_s_setprio(1);
            s0 = MFMA16(k0, qf[0][0], s0);
            s0 = MFMA16(k1, qf[0][1], s0);
            s1 = MFMA16(k0, qf[1][0], s1);
            s1 = MFMA16(k1, qf[1][1], s1);
            __builtin_amdgcn_s_setprio(0);
            float p0[4], p1[4];
#pragma unroll
            for (int r = 0; r < 4; r++) {
                p0[r] = __builtin_amdgcn_exp2f(s0[r]);
                p1[r] = __builtin_amdgcn_exp2f(s1[r]);
            }
            lsum[0] += (p0[0] + p0[1]) + (p0[2] + p0[3]);
            lsum[1] += (p1[0] + p1[1]) + (p1[2] + p1[3]);
            if (!(mf & 1)) {
                pwA[0] = __builtin_amdgcn_perm(fbits(p0[1]), fbits(p0[0]), 0x07060302u);
                pwA[1] = __builtin_amdgcn_perm(fbits(p0[3]), fbits(p0[2]), 0x07060302u);
                pwB[0] = __builtin_amdgcn_perm(fbits(p1[1]), fbits(p1[0]), 0x07060302u);
                pwB[1] = __builtin_amdgcn_perm(fbits(p1[3]), fbits(p1[2]), 0x07060302u);
            } else {
                pwA[2] = __builtin_amdgcn_perm(fbits(p0[1]), fbits(p0[0]), 0x07060302u);
                pwA[3] = __builtin_amdgcn_perm(fbits(p0[3]), fbits(p0[2]), 0x07060302u);
                pwB[2] = __builtin_amdgcn_perm(fbits(p1[1]), fbits(p1[0]), 0x07060302u);
                pwB[3] = __builtin_amdgcn_perm(fbits(p1[3]), fbits(p1[2]), 0x07060302u);
                pb[0][mf >> 1] = __builtin_bit_cast(short8v, pwA);
                pb[1][mf >> 1] = __builtin_bit_cast(short8v, pwB);
            }
        }

        __builtin_amdgcn_s_setprio(1);
#pragma unroll
        for (int mh = 0; mh < 2; mh++)
#pragma unroll
            for (int dg = 0; dg < 4; dg++) {
                short8v vf = *(const short8v*)(vl + ((mh * 4 + lg) * 64 + dg * 16 + l15) * 8);
                od[0][dg] = MFMA16(vf, pb[0][mh], od[0][dg]);
                od[1][dg] = MFMA16(vf, pb[1][mh], od[1][dg]);
            }
        __builtin_amdgcn_s_setprio(0);

        __builtin_amdgcn_s_barrier();
        u ^= 1;
    }
#undef STAGE

#pragma unroll
    for (int ng = 0; ng < 2; ng++) {
        lsum[ng] += __shfl_xor(lsum[ng], 16, 64);
        lsum[ng] += __shfl_xor(lsum[ng], 32, 64);
    }

    unsigned short* op = opart + (((size_t)(seg * 8 + h)) * 4096 + nu * 32) * 64;
#pragma unroll
    for (int ng = 0; ng < 2; ng++)
#pragma unroll
        for (int dg = 0; dg < 4; dg++) {
            unsigned short v4[4];
#pragma unroll
            for (int r = 0; r < 4; r++) v4[r] = bf16r(od[ng][dg][r]);
            *(short4v*)(op + (ng * 16 + l15) * 64 + dg * 16 + 4 * lg) = *(const short4v*)v4;
        }
    if (lg == 0) {
#pragma unroll
        for (int ng = 0; ng < 2; ng++)
            lgl[(size_t)(seg * 8 + h) * 4096 + nu * 32 + ng * 16 + l15] = lsum[ng];
    }
}

// ---------------- merge 4 seg partials -> attn_bT (n-major), coalesced ----------------
__global__ __launch_bounds__(256) void k_merge(const unsigned short* __restrict__ opart,
                                               const float* __restrict__ lgl,
                                               unsigned short* __restrict__ attn_bT) {
    int t = threadIdx.x;
    int n = blockIdx.x * 8 + (t >> 5);
    int cid = t & 31;
    int h = cid >> 2, d0 = (cid & 3) * 16;

    float den = 0.f;
    float num[16] = {};
#pragma unroll
    for (int s = 0; s < 4; s++) {
        den += lgl[(size_t)(s * 8 + h) * 4096 + n];
        const unsigned short* row = opart + (((size_t)(s * 8 + h)) * 4096 + n) * 64 + d0;
        short8v a = *(const short8v*)row;
        short8v b = *(const short8v*)(row + 8);
#pragma unroll
        for (int j = 0; j < 8; j++) {
            num[j] += bff((unsigned short)a[j]);
            num[8 + j] += bff((unsigned short)b[j]);
        }
    }
    float inv = 1.0f / den;
    unsigned short res[16];
#pragma unroll
    for (int j = 0; j < 16; j++) res[j] = bf16r(num[j] * inv);
    unsigned short* dst = attn_bT + (size_t)n * 512 + h * 64 + d0;
    *(short8v*)dst = *(const short8v*)&res[0];
    *(short8v*)(dst + 8) = *(const short8v*)&res[8];
}

// ---------------- proj GEMM: C[512,4096] = A[512,512] x BT[4096,512]^T ----------------
__global__ __launch_bounds__(256) void k_gemmT(const unsigned short* __restrict__ A,
                                               const unsigned short* __restrict__ BT,
                                               unsigned short* __restrict__ C) {
    __shared__ unsigned short As[64][36];
    __shared__ unsigned short Bs[128][36];
    int t = threadIdx.x;
    int w = t >> 6, l = t & 63, l15 = l & 15, lg = l >> 4;
    int wrow = w >> 1, wcol = w & 1;
    int m0 = blockIdx.y * 64, n0 = blockIdx.x * 128;
    f32x4 acc[2][4] = {};

    for (int k0 = 0; k0 < 512; k0 += 32) {
#pragma unroll
        for (int i = 0; i < 2; i++) {
            int idx = t + 256 * i;
            int row = idx >> 3, kc = idx & 7;
            short4v av = *(const short4v*)(A + (size_t)(m0 + row) * 512 + k0 + 4 * kc);
            *(short4v*)&As[row][4 * kc] = av;
        }
#pragma unroll
        for (int i = 0; i < 4; i++) {
            int idx = t + 256 * i;
            int row = idx >> 3, kc = idx & 7;
            short4v bv = *(const short4v*)(BT + (size_t)(n0 + row) * 512 + k0 + 4 * kc);
            *(short4v*)&Bs[row][4 * kc] = bv;
        }
        __syncthreads();

        short8v af[2];
#pragma unroll
        for (int mi = 0; mi < 2; mi++) {
            int ar = wrow * 32 + mi * 16 + l15;
            short4v a0 = *(const short4v*)&As[ar][4 * lg];
            short4v a1 = *(const short4v*)&As[ar][16 + 4 * lg];
            af[mi] = __builtin_shufflevector(a0, a1, 0, 1, 2, 3, 4, 5, 6, 7);
        }
#pragma unroll
        for (int ni = 0; ni < 4; ni++) {
            int bc = wcol * 64 + ni * 16 + l15;
            short4v b0 = *(const short4v*)&Bs[bc][4 * lg];
            short4v b1 = *(const short4v*)&Bs[bc][16 + 4 * lg];
            short8v bf = __builtin_shufflevector(b0, b1, 0, 1, 2, 3, 4, 5, 6, 7);
#pragma unroll
            for (int mi = 0; mi < 2; mi++) acc[mi][ni] = MFMA16(af[mi], bf, acc[mi][ni]);
        }
        __syncthreads();
    }
#pragma unroll
    for (int mi = 0; mi < 2; mi++)
#pragma unroll
        for (int ni = 0; ni < 4; ni++) {
            int row = m0 + wrow * 32 + mi * 16 + 4 * lg;
            int col = n0 + wcol * 64 + ni * 16 + l15;
#pragma unroll
            for (int r = 0; r < 4; r++)
                C[(size_t)(row + r) * 4096 + col] = bf16r(acc[mi][ni][r]);
        }
}

// ---------------- bilinear upsample + bias + residual (NT load/store, shfl neighbors) ----------------
__global__ __launch_bounds__(256) void k_up(const float* __restrict__ x,
                                            const unsigned short* __restrict__ low,
                                            const float* __restrict__ proj_b,
                                            const float* __restrict__ gamma,
                                            float* __restrict__ out) {
    int t = threadIdx.x;
    int hs = t >> 6;
    int hh = blockIdx.x * 4 + hs;
    int c = blockIdx.y;
    int a = t & 63;

    int ph = hh & 3, Ah = hh >> 2;
    int y0 = Ah + ((ph < 2) ? -1 : 0);
    float fy = (ph < 2) ? (0.625f + 0.25f * ph) : (0.125f + 0.25f * (ph - 2));
    int y1 = min(y0 + 1, 63); y0 = max(y0, 0);

    const unsigned short* L0 = low + (size_t)c * 4096 + y0 * 64;
    const unsigned short* L1 = low + (size_t)c * 4096 + y1 * 64;
    float gy = 1.f - fy;
    float v0 = gy * bff(L0[a]) + fy * bff(L1[a]);
    float vmu = __shfl_up(v0, 1, 64);
    float vpd = __shfl_down(v0, 1, 64);
    float vm = (a == 0) ? v0 : vmu;
    float vp = (a == 63) ? v0 : vpd;

    float pb = proj_b[c], g = gamma[0];
    size_t idx = (size_t)c * 65536 + (size_t)hh * 256 + a * 4;
    f32x4 xi = __builtin_nontemporal_load((const f32x4*)(x + idx));
    f32x4 o;
    o[0] = xi[0] + g * (0.375f * vm + 0.625f * v0 + pb);
    o[1] = xi[1] + g * (0.125f * vm + 0.875f * v0 + pb);
    o[2] = xi[2] + g * (0.875f * v0 + 0.125f * vp + pb);
    o[3] = xi[3] + g * (0.625f * v0 + 0.375f * vp + pb);
    __builtin_nontemporal_store(o, (f32x4*)(out + idx));
}

extern "C" void kernel_launch(void* const* d_in, const int* in_sizes, int n_in,
                              void* d_out, int out_size, void* d_ws, size_t ws_size,
                              hipStream_t stream) {
    const float* x     = (const float*)d_in[0];
    const float* gnw   = (const float*)d_in[1];
    const float* gnb   = (const float*)d_in[2];
    const float* qkvw  = (const float*)d_in[3];
    const float* projw = (const float*)d_in[4];
    const float* projb = (const float*)d_in[5];
    const float* gamma = (const float*)d_in[6];
    const float* temp  = (const float*)d_in[7];

    char* ws = (char*)d_ws;
    const size_t MB = 1u << 20;
    float* gstats          = (float*)(ws + 0);
    int* cnt               = (int*)(ws + 512);
    float* partials        = (float*)(ws + 1024);
    float* xp              = (float*)(ws + 1 * MB);            // dead after k_xr
    unsigned short* qtg    = (unsigned short*)(ws + 1 * MB);   // reuses xp (4MB)
    unsigned short* ktg    = (unsigned short*)(ws + 5 * MB);   // 4MB
    unsigned short* xr_b   = (unsigned short*)(ws + 9 * MB);   // live through gemmP
    unsigned short* vtg    = (unsigned short*)(ws + 13 * MB);  // 4MB
    unsigned short* wq_b   = (unsigned short*)(ws + 17 * MB);
    unsigned short* wp_b   = (unsigned short*)(ws + 19 * MB);
    unsigned short* attn_bT= (unsigned short*)(ws + 21 * MB);  // n-major (4096,512)
    unsigned short* low_b  = (unsigned short*)(ws + 25 * MB);
    float* out = (float*)d_out;
    unsigned short* opart = (unsigned short*)d_out;              // 16MB scratch in d_out
    float* lgl = (float*)((char*)d_out + 16 * MB);               // 0.5MB scratch in d_out

    (void)hipMemsetAsync(cnt, 0, sizeof(int), stream);
    k_pool<<<dim3(72, 512), 256, 0, stream>>>(x, xp, partials, qkvw, projw, temp,
                                              wq_b, wp_b, cnt, gstats);
    k_xr<<<8192, 256, 0, stream>>>(xp, gstats, gnw, gnb, xr_b);
    k_gemmP<<<dim3(32, 12), 256, 0, stream>>>(wq_b, xr_b, qtg, ktg, vtg);
    k_attn<<<dim3(32, 8, 4), 256, 0, stream>>>(qtg, ktg, vtg, opart, lgl);
    k_merge<<<512, 256, 0, stream>>>(opart, lgl, attn_bT);
    k_gemmT<<<dim3(32, 8), 256, 0, stream>>>(wp_b, attn_bT, low_b);
    k_up<<<dim3(64, 512), 256, 0, stream>>>(x, low_b, projb, gamma, out);
}

// Round 13
// 192.050 us; speedup vs baseline: 6.8709x; 6.8709x over previous
//
#include <hip/hip_runtime.h>
#include <hip/hip_bf16.h>

// Pipeline (8 launches):
//  k_pool   : x -> pooled xp + group partials [+ fused wconv]  (NT x-load; NO fence/atomic)
//  k_stats  : reduce partials -> mean/rstd per group (separate tiny launch)
//  k_xr     : xr = GN_affine(xp) + posenc -> bf16 (512,4096)
//  k_gemmP  : qkv = Wq(1536,512) x xr -> fragment-ordered qtg/ktg/vtg directly
//  k_attn   : flash attn, m==0 softmax, lane-local l, 64-key tiles, dbuf LDS,
//             counted vmcnt, 4 segments (grid 1024 = 4 blocks/CU)
//  k_merge  : sum 4 seg partials -> attn_bT (n-major) bf16
//  k_gemmT  : low = Wp(512,512) x attn_bT^T, 64-row tiles (grid 256)
//  k_up     : out = x + gamma*(bilerp_4x(low)+proj_b); NT x-load, shfl neighbors, NT store

typedef __attribute__((ext_vector_type(4))) short short4v;
typedef __attribute__((ext_vector_type(8))) short short8v;
typedef __attribute__((ext_vector_type(4))) float f32x4;
typedef __attribute__((ext_vector_type(4))) unsigned int u32x4;

#define MFMA16(a, b, c) __builtin_amdgcn_mfma_f32_16x16x32_bf16(a, b, c, 0, 0, 0)

__device__ __forceinline__ unsigned short bf16r(float f) {
    unsigned int u = __builtin_bit_cast(unsigned int, f);
    u += 0x7fffu + ((u >> 16) & 1u);
    return (unsigned short)(u >> 16);
}
__device__ __forceinline__ float bff(unsigned short s) {
    unsigned int u = ((unsigned int)s) << 16;
    return __builtin_bit_cast(float, u);
}
__device__ __forceinline__ unsigned int fbits(float f) {
    return __builtin_bit_cast(unsigned int, f);
}

typedef const __attribute__((address_space(1))) unsigned int guint;
typedef __attribute__((address_space(3))) unsigned int luint;
__device__ __forceinline__ void gload16(const void* g, void* l) {
    __builtin_amdgcn_global_load_lds((guint*)g, (luint*)l, 16, 0, 0);
}

// ---------------- pool + group partial stats (+ fused weight conversion) ----------------
__global__ __launch_bounds__(256) void k_pool(const float* __restrict__ x,
                                              float* __restrict__ xp,
                                              float* __restrict__ partials,
                                              const float* __restrict__ qkv_w,
                                              const float* __restrict__ proj_w,
                                              const float* __restrict__ temp,
                                              unsigned short* __restrict__ wq_b,
                                              unsigned short* __restrict__ wp_b) {
    int t = threadIdx.x;
    if (blockIdx.x >= 64) {
        int idx = ((blockIdx.x - 64) * 512 + blockIdx.y) * 256 + t;
        const int NQ = 1536 * 512;
        const int NTOT = NQ + 512 * 512;
        if (idx < NQ) {
            int o = idx >> 9;
            float sc = (o < 512) ? temp[o >> 6] * 0.125f * 1.44269504f : 1.0f;
            wq_b[idx] = bf16r(qkv_w[idx] * sc);
        } else if (idx < NTOT) {
            wp_b[idx - NQ] = bf16r(proj_w[idx - NQ]);
        }
        return;
    }
    int hr = blockIdx.x;
    int c  = blockIdx.y;
    int r = t >> 6, wq = t & 63;
    const f32x4* src = (const f32x4*)(x + (size_t)c * 65536 + (size_t)(4 * hr + r) * 256 + 4 * wq);
    f32x4 v = __builtin_nontemporal_load(src);
    float s4 = v[0] + v[1] + v[2] + v[3];
    float q4 = v[0] * v[0] + v[1] * v[1] + v[2] * v[2] + v[3] * v[3];

    __shared__ float sm[256];
    __shared__ float wq4[4];
    sm[t] = s4;
    float qq = q4;
#pragma unroll
    for (int off = 1; off < 64; off <<= 1) qq += __shfl_xor(qq, off, 64);
    if ((t & 63) == 0) wq4[t >> 6] = qq;
    __syncthreads();
    if (t < 64) {
        float cs = sm[t] + sm[64 + t] + sm[128 + t] + sm[192 + t];
        xp[(size_t)c * 4096 + hr * 64 + t] = cs * (1.0f / 16.0f);
        float ts = cs;
#pragma unroll
        for (int off = 1; off < 64; off <<= 1) ts += __shfl_xor(ts, off, 64);
        if (t == 0) {
            int g = c >> 6;
            int slot = (c & 63) * 64 + hr;
            partials[(size_t)(g * 4096 + slot) * 2 + 0] = ts;
            partials[(size_t)(g * 4096 + slot) * 2 + 1] = wq4[0] + wq4[1] + wq4[2] + wq4[3];
        }
    }
}

// ---------------- group stats finalize ----------------
__global__ __launch_bounds__(256) void k_stats(const float* __restrict__ partials,
                                               float* __restrict__ gstats) {
    int g = blockIdx.x;
    int t = threadIdx.x;
    float s = 0.f, q = 0.f;
    for (int i = t; i < 4096; i += 256) {
        s += partials[(size_t)(g * 4096 + i) * 2 + 0];
        q += partials[(size_t)(g * 4096 + i) * 2 + 1];
    }
#pragma unroll
    for (int off = 1; off < 64; off <<= 1) {
        s += __shfl_xor(s, off, 64);
        q += __shfl_xor(q, off, 64);
    }
    __shared__ float ss[4], qs[4];
    if ((t & 63) == 0) { ss[t >> 6] = s; qs[t >> 6] = q; }
    __syncthreads();
    if (t == 0) {
        float S = ss[0] + ss[1] + ss[2] + ss[3];
        float Q = qs[0] + qs[1] + qs[2] + qs[3];
        const float inv = 1.0f / 4194304.0f;
        float m = S * inv;
        float var = Q * inv - m * m;
        gstats[2 * g] = m;
        gstats[2 * g + 1] = rsqrtf(var + 1e-5f);
    }
}

// ---------------- GN affine + positional encoding -> bf16 ----------------
__global__ __launch_bounds__(256) void k_xr(const float* __restrict__ xp,
                                            const float* __restrict__ gs,
                                            const float* __restrict__ gw,
                                            const float* __restrict__ gb,
                                            unsigned short* __restrict__ xr) {
    int idx = blockIdx.x * 256 + threadIdx.x;
    int c = idx >> 12, n = idx & 4095;
    int hr = n >> 6, wr = n & 63;
    int g = c >> 6;
    float m = gs[2 * g], rs = gs[2 * g + 1];
    float xn = (xp[idx] - m) * rs * gw[c] + gb[c];
    int i = c >> 2, kind = c & 3;
    float di = expf(-(float)i * 0.07195578415606394f);
    float arg = ((kind < 2) ? (float)hr : (float)wr) * di;
    float pe = 0.01f * ((kind & 1) ? cosf(arg) : sinf(arg));
    xr[idx] = bf16r(xn + pe);
}

// ---------------- QKV GEMM with fused fragment-order epilogue ----------------
__global__ __launch_bounds__(256) void k_gemmP(const unsigned short* __restrict__ A,
                                               const unsigned short* __restrict__ B,
                                               unsigned short* __restrict__ qtg,
                                               unsigned short* __restrict__ ktg,
                                               unsigned short* __restrict__ vtg) {
    __shared__ __align__(16) char smem[33792];
    unsigned short (*As)[36] = (unsigned short(*)[36])smem;
    unsigned short (*Bs)[36] = (unsigned short(*)[36])(smem + 9216);
    unsigned short (*ct)[132] = (unsigned short(*)[132])smem;  // epilogue reuse

    int t = threadIdx.x;
    int w = t >> 6, l = t & 63, l15 = l & 15, lg = l >> 4;
    int wrow = w >> 1, wcol = w & 1;
    int m0 = blockIdx.y * 128, n0 = blockIdx.x * 128;
    f32x4 acc[4][4] = {};

    for (int k0 = 0; k0 < 512; k0 += 32) {
#pragma unroll
        for (int i = 0; i < 4; i++) {
            int idx = t + 256 * i;
            int row = idx >> 3, kc = idx & 7;
            short4v av = *(const short4v*)(A + (size_t)(m0 + row) * 512 + k0 + 4 * kc);
            *(short4v*)&As[row][4 * kc] = av;
        }
#pragma unroll
        for (int i = 0; i < 4; i++) {
            int idx = t + 256 * i;
            int kr = idx >> 5, nc = idx & 31;
            short4v bv = *(const short4v*)(B + (size_t)(k0 + kr) * 4096 + n0 + 4 * nc);
#pragma unroll
            for (int j = 0; j < 4; j++) Bs[4 * nc + j][kr] = (unsigned short)bv[j];
        }
        __syncthreads();

        short8v af[4];
#pragma unroll
        for (int mi = 0; mi < 4; mi++) {
            int ar = wrow * 64 + mi * 16 + l15;
            short4v a0 = *(const short4v*)&As[ar][4 * lg];
            short4v a1 = *(const short4v*)&As[ar][16 + 4 * lg];
            af[mi] = __builtin_shufflevector(a0, a1, 0, 1, 2, 3, 4, 5, 6, 7);
        }
#pragma unroll
        for (int ni = 0; ni < 4; ni++) {
            int bc = wcol * 64 + ni * 16 + l15;
            short4v b0 = *(const short4v*)&Bs[bc][4 * lg];
            short4v b1 = *(const short4v*)&Bs[bc][16 + 4 * lg];
            short8v bf = __builtin_shufflevector(b0, b1, 0, 1, 2, 3, 4, 5, 6, 7);
#pragma unroll
            for (int mi = 0; mi < 4; mi++) acc[mi][ni] = MFMA16(af[mi], bf, acc[mi][ni]);
        }
        __syncthreads();
    }

#pragma unroll
    for (int mi = 0; mi < 4; mi++)
#pragma unroll
        for (int ni = 0; ni < 4; ni++) {
            int ml = wrow * 64 + mi * 16 + 4 * lg;
            int nl = wcol * 64 + ni * 16 + l15;
#pragma unroll
            for (int r = 0; r < 4; r++) ct[ml + r][nl] = bf16r(acc[mi][ni][r]);
        }
    __syncthreads();

    int y = blockIdx.y;
#pragma unroll
    for (int i = 0; i < 8; i++) {
        int gc = t + 256 * i;  // [0, 2048)
        int hg = gc >> 10, rem = gc & 1023;
        unsigned short o[8];
        unsigned short* dst;
        if (y < 4) {  // Q
            int nu_loc = rem >> 8, cidx = rem & 255;
            int s = cidx >> 7, lgc = (cidx >> 5) & 3, col = cidx & 31;
#pragma unroll
            for (int j = 0; j < 4; j++) {
                o[j] = ct[hg * 64 + s * 32 + 4 * lgc + j][nu_loc * 32 + col];
                o[4 + j] = ct[hg * 64 + s * 32 + 16 + 4 * lgc + j][nu_loc * 32 + col];
            }
            int h = y * 2 + hg;
            dst = qtg + ((size_t)(h * 128 + (n0 >> 5) + nu_loc)) * 2048 + cidx * 8;
        } else if (y < 8) {  // K
            int Tloc = rem >> 9, cidx = rem & 511;
            int s = cidx >> 8, lgc = (cidx >> 6) & 3, m64 = cidx & 63;
#pragma unroll
            for (int j = 0; j < 4; j++) {
                o[j] = ct[hg * 64 + s * 32 + 4 * lgc + j][Tloc * 64 + m64];
                o[4 + j] = ct[hg * 64 + s * 32 + 16 + 4 * lgc + j][Tloc * 64 + m64];
            }
            int h = (y - 4) * 2 + hg;
            dst = ktg + ((size_t)(h * 64 + (n0 >> 6) + Tloc)) * 4096 + cidx * 8;
        } else {  // V
            int Tloc = rem >> 9, cidx = rem & 511;
            int mh = cidx >> 8, lgc = (cidx >> 6) & 3, d = cidx & 63;
#pragma unroll
            for (int j = 0; j < 4; j++) {
                o[j] = ct[hg * 64 + d][Tloc * 64 + mh * 32 + 4 * lgc + j];
                o[4 + j] = ct[hg * 64 + d][Tloc * 64 + mh * 32 + 16 + 4 * lgc + j];
            }
            int h = (y - 8) * 2 + hg;
            dst = vtg + ((size_t)(h * 64 + (n0 >> 6) + Tloc)) * 4096 + cidx * 8;
        }
        *(short8v*)dst = *(const short8v*)o;
    }
}

// ---------------- flash attention: 4 segs, dbuf, counted vmcnt ----------------
__global__ __launch_bounds__(256, 5) void k_attn(const unsigned short* __restrict__ qtg,
                                                 const unsigned short* __restrict__ ktg,
                                                 const unsigned short* __restrict__ vtg,
                                                 unsigned short* __restrict__ opart,
                                                 float* __restrict__ lgl) {
    __shared__ __align__(16) unsigned short kbuf[2][4096];
    __shared__ __align__(16) unsigned short vbuf[2][4096];
    int t = threadIdx.x;
    int l = t & 63, l15 = l & 15, lg = l >> 4, w = t >> 6;
    int qt = blockIdx.x, h = blockIdx.y, seg = blockIdx.z;
    int nu = qt * 4 + w;

    const unsigned short* qb = qtg + ((size_t)(h * 128 + nu)) * 2048;
    const unsigned short* kb = ktg + ((size_t)(h * 64 + seg * 16)) * 4096;
    const unsigned short* vb = vtg + ((size_t)(h * 64 + seg * 16)) * 4096;

    short8v qf[2][2];
#pragma unroll
    for (int ng = 0; ng < 2; ng++)
#pragma unroll
        for (int s = 0; s < 2; s++)
            qf[ng][s] = *(const short8v*)(qb + ((s * 4 + lg) * 32 + ng * 16 + l15) * 8);

    f32x4 od[2][4] = {};
    float lsum[2] = {0.f, 0.f};

#define STAGE(kt, b)                                                            \
    {                                                                           \
        gload16(kb + (size_t)(kt) * 4096 + t * 8, &kbuf[b][t * 8]);             \
        gload16(kb + (size_t)(kt) * 4096 + (t + 256) * 8, &kbuf[b][(t + 256) * 8]); \
        gload16(vb + (size_t)(kt) * 4096 + t * 8, &vbuf[b][t * 8]);             \
        gload16(vb + (size_t)(kt) * 4096 + (t + 256) * 8, &vbuf[b][(t + 256) * 8]); \
    }

    STAGE(0, 0);

    int u = 0;
#pragma unroll 1
    for (int j = 0; j < 16; j++) {
        if (j < 15) {
            STAGE(j + 1, u ^ 1);
            asm volatile("s_waitcnt vmcnt(4)" ::: "memory");
        } else {
            asm volatile("s_waitcnt vmcnt(0)" ::: "memory");
        }
        __builtin_amdgcn_s_barrier();
        __builtin_amdgcn_sched_barrier(0);

        const unsigned short* kl = &kbuf[u][0];
        const unsigned short* vl = &vbuf[u][0];

        u32x4 pwA, pwB;
        short8v pb[2][2];
#pragma unroll
        for (int mf = 0; mf < 4; mf++) {
            short8v k0 = *(const short8v*)(kl + ((0 + lg) * 64 + mf * 16 + l15) * 8);
            short8v k1 = *(const short8v*)(kl + ((4 + lg) * 64 + mf * 16 + l15) * 8);
            f32x4 s0 = {}, s1 = {};
            __builtin_amdgcn_s_setprio(1);
            s0 = MFMA16(k0, qf[0][0], s0);
            s0 = MFMA16(k1, qf[0][1], s0);
            s1 = MFMA16(k0, qf[1][0], s1);
            s1 = MFMA16(k1, qf[1][1], s1);
            __builtin_amdgcn_s_setprio(0);
            float p0[4], p1[4];
#pragma unroll
            for (int r = 0; r < 4; r++) {
                p0[r] = __builtin_amdgcn_exp2f(s0[r]);
                p1[r] = __builtin_amdgcn_exp2f(s1[r]);
            }
            lsum[0] += (p0[0] + p0[1]) + (p0[2] + p0[3]);
            lsum[1] += (p1[0] + p1[1]) + (p1[2] + p1[3]);
            if (!(mf & 1)) {
                pwA[0] = __builtin_amdgcn_perm(fbits(p0[1]), fbits(p0[0]), 0x07060302u);
                pwA[1] = __builtin_amdgcn_perm(fbits(p0[3]), fbits(p0[2]), 0x07060302u);
                pwB[0] = __builtin_amdgcn_perm(fbits(p1[1]), fbits(p1[0]), 0x07060302u);
                pwB[1] = __builtin_amdgcn_perm(fbits(p1[3]), fbits(p1[2]), 0x07060302u);
            } else {
                pwA[2] = __builtin_amdgcn_perm(fbits(p0[1]), fbits(p0[0]), 0x07060302u);
                pwA[3] = __builtin_amdgcn_perm(fbits(p0[3]), fbits(p0[2]), 0x07060302u);
                pwB[2] = __builtin_amdgcn_perm(fbits(p1[1]), fbits(p1[0]), 0x07060302u);
                pwB[3] = __builtin_amdgcn_perm(fbits(p1[3]), fbits(p1[2]), 0x07060302u);
                pb[0][mf >> 1] = __builtin_bit_cast(short8v, pwA);
                pb[1][mf >> 1] = __builtin_bit_cast(short8v, pwB);
            }
        }

        __builtin_amdgcn_s_setprio(1);
#pragma unroll
        for (int mh = 0; mh < 2; mh++)
#pragma unroll
            for (int dg = 0; dg < 4; dg++) {
                short8v vf = *(const short8v*)(vl + ((mh * 4 + lg) * 64 + dg * 16 + l15) * 8);
                od[0][dg] = MFMA16(vf, pb[0][mh], od[0][dg]);
                od[1][dg] = MFMA16(vf, pb[1][mh], od[1][dg]);
            }
        __builtin_amdgcn_s_setprio(0);

        __builtin_amdgcn_s_barrier();
        u ^= 1;
    }
#undef STAGE

#pragma unroll
    for (int ng = 0; ng < 2; ng++) {
        lsum[ng] += __shfl_xor(lsum[ng], 16, 64);
        lsum[ng] += __shfl_xor(lsum[ng], 32, 64);
    }

    unsigned short* op = opart + (((size_t)(seg * 8 + h)) * 4096 + nu * 32) * 64;
#pragma unroll
    for (int ng = 0; ng < 2; ng++)
#pragma unroll
        for (int dg = 0; dg < 4; dg++) {
            unsigned short v4[4];
#pragma unroll
            for (int r = 0; r < 4; r++) v4[r] = bf16r(od[ng][dg][r]);
            *(short4v*)(op + (ng * 16 + l15) * 64 + dg * 16 + 4 * lg) = *(const short4v*)v4;
        }
    if (lg == 0) {
#pragma unroll
        for (int ng = 0; ng < 2; ng++)
            lgl[(size_t)(seg * 8 + h) * 4096 + nu * 32 + ng * 16 + l15] = lsum[ng];
    }
}

// ---------------- merge 4 seg partials -> attn_bT (n-major), coalesced ----------------
__global__ __launch_bounds__(256) void k_merge(const unsigned short* __restrict__ opart,
                                               const float* __restrict__ lgl,
                                               unsigned short* __restrict__ attn_bT) {
    int t = threadIdx.x;
    int n = blockIdx.x * 8 + (t >> 5);
    int cid = t & 31;
    int h = cid >> 2, d0 = (cid & 3) * 16;

    float den = 0.f;
    float num[16] = {};
#pragma unroll
    for (int s = 0; s < 4; s++) {
        den += lgl[(size_t)(s * 8 + h) * 4096 + n];
        const unsigned short* row = opart + (((size_t)(s * 8 + h)) * 4096 + n) * 64 + d0;
        short8v a = *(const short8v*)row;
        short8v b = *(const short8v*)(row + 8);
#pragma unroll
        for (int j = 0; j < 8; j++) {
            num[j] += bff((unsigned short)a[j]);
            num[8 + j] += bff((unsigned short)b[j]);
        }
    }
    float inv = 1.0f / den;
    unsigned short res[16];
#pragma unroll
    for (int j = 0; j < 16; j++) res[j] = bf16r(num[j] * inv);
    unsigned short* dst = attn_bT + (size_t)n * 512 + h * 64 + d0;
    *(short8v*)dst = *(const short8v*)&res[0];
    *(short8v*)(dst + 8) = *(const short8v*)&res[8];
}

// ---------------- proj GEMM: C[512,4096] = A[512,512] x BT[4096,512]^T ----------------
__global__ __launch_bounds__(256) void k_gemmT(const unsigned short* __restrict__ A,
                                               const unsigned short* __restrict__ BT,
                                               unsigned short* __restrict__ C) {
    __shared__ unsigned short As[64][36];
    __shared__ unsigned short Bs[128][36];
    int t = threadIdx.x;
    int w = t >> 6, l = t & 63, l15 = l & 15, lg = l >> 4;
    int wrow = w >> 1, wcol = w & 1;
    int m0 = blockIdx.y * 64, n0 = blockIdx.x * 128;
    f32x4 acc[2][4] = {};

    for (int k0 = 0; k0 < 512; k0 += 32) {
#pragma unroll
        for (int i = 0; i < 2; i++) {
            int idx = t + 256 * i;
            int row = idx >> 3, kc = idx & 7;
            short4v av = *(const short4v*)(A + (size_t)(m0 + row) * 512 + k0 + 4 * kc);
            *(short4v*)&As[row][4 * kc] = av;
        }
#pragma unroll
        for (int i = 0; i < 4; i++) {
            int idx = t + 256 * i;
            int row = idx >> 3, kc = idx & 7;
            short4v bv = *(const short4v*)(BT + (size_t)(n0 + row) * 512 + k0 + 4 * kc);
            *(short4v*)&Bs[row][4 * kc] = bv;
        }
        __syncthreads();

        short8v af[2];
#pragma unroll
        for (int mi = 0; mi < 2; mi++) {
            int ar = wrow * 32 + mi * 16 + l15;
            short4v a0 = *(const short4v*)&As[ar][4 * lg];
            short4v a1 = *(const short4v*)&As[ar][16 + 4 * lg];
            af[mi] = __builtin_shufflevector(a0, a1, 0, 1, 2, 3, 4, 5, 6, 7);
        }
#pragma unroll
        for (int ni = 0; ni < 4; ni++) {
            int bc = wcol * 64 + ni * 16 + l15;
            short4v b0 = *(const short4v*)&Bs[bc][4 * lg];
            short4v b1 = *(const short4v*)&Bs[bc][16 + 4 * lg];
            short8v bf = __builtin_shufflevector(b0, b1, 0, 1, 2, 3, 4, 5, 6, 7);
#pragma unroll
            for (int mi = 0; mi < 2; mi++) acc[mi][ni] = MFMA16(af[mi], bf, acc[mi][ni]);
        }
        __syncthreads();
    }
#pragma unroll
    for (int mi = 0; mi < 2; mi++)
#pragma unroll
        for (int ni = 0; ni < 4; ni++) {
            int row = m0 + wrow * 32 + mi * 16 + 4 * lg;
            int col = n0 + wcol * 64 + ni * 16 + l15;
#pragma unroll
            for (int r = 0; r < 4; r++)
                C[(size_t)(row + r) * 4096 + col] = bf16r(acc[mi][ni][r]);
        }
}

// ---------------- bilinear upsample + bias + residual (NT load/store, shfl neighbors) ----------------
__global__ __launch_bounds__(256) void k_up(const float* __restrict__ x,
                                            const unsigned short* __restrict__ low,
                                            const float* __restrict__ proj_b,
                                            const float* __restrict__ gamma,
                                            float* __restrict__ out) {
    int t = threadIdx.x;
    int hs = t >> 6;
    int hh = blockIdx.x * 4 + hs;
    int c = blockIdx.y;
    int a = t & 63;

    int ph = hh & 3, Ah = hh >> 2;
    int y0 = Ah + ((ph < 2) ? -1 : 0);
    float fy = (ph < 2) ? (0.625f + 0.25f * ph) : (0.125f + 0.25f * (ph - 2));
    int y1 = min(y0 + 1, 63); y0 = max(y0, 0);

    const unsigned short* L0 = low + (size_t)c * 4096 + y0 * 64;
    const unsigned short* L1 = low + (size_t)c * 4096 + y1 * 64;
    float gy = 1.f - fy;
    float v0 = gy * bff(L0[a]) + fy * bff(L1[a]);
    float vmu = __shfl_up(v0, 1, 64);
    float vpd = __shfl_down(v0, 1, 64);
    float vm = (a == 0) ? v0 : vmu;
    float vp = (a == 63) ? v0 : vpd;

    float pb = proj_b[c], g = gamma[0];
    size_t idx = (size_t)c * 65536 + (size_t)hh * 256 + a * 4;
    f32x4 xi = __builtin_nontemporal_load((const f32x4*)(x + idx));
    f32x4 o;
    o[0] = xi[0] + g * (0.375f * vm + 0.625f * v0 + pb);
    o[1] = xi[1] + g * (0.125f * vm + 0.875f * v0 + pb);
    o[2] = xi[2] + g * (0.875f * v0 + 0.125f * vp + pb);
    o[3] = xi[3] + g * (0.625f * v0 + 0.375f * vp + pb);
    __builtin_nontemporal_store(o, (f32x4*)(out + idx));
}

extern "C" void kernel_launch(void* const* d_in, const int* in_sizes, int n_in,
                              void* d_out, int out_size, void* d_ws, size_t ws_size,
                              hipStream_t stream) {
    const float* x     = (const float*)d_in[0];
    const float* gnw   = (const float*)d_in[1];
    const float* gnb   = (const float*)d_in[2];
    const float* qkvw  = (const float*)d_in[3];
    const float* projw = (const float*)d_in[4];
    const float* projb = (const float*)d_in[5];
    const float* gamma = (const float*)d_in[6];
    const float* temp  = (const float*)d_in[7];

    char* ws = (char*)d_ws;
    const size_t MB = 1u << 20;
    float* gstats          = (float*)(ws + 0);
    float* partials        = (float*)(ws + 1024);
    float* xp              = (float*)(ws + 1 * MB);            // dead after k_xr
    unsigned short* qtg    = (unsigned short*)(ws + 1 * MB);   // reuses xp (4MB)
    unsigned short* ktg    = (unsigned short*)(ws + 5 * MB);   // 4MB
    unsigned short* xr_b   = (unsigned short*)(ws + 9 * MB);   // live through gemmP
    unsigned short* vtg    = (unsigned short*)(ws + 13 * MB);  // 4MB
    unsigned short* wq_b   = (unsigned short*)(ws + 17 * MB);
    unsigned short* wp_b   = (unsigned short*)(ws + 19 * MB);
    unsigned short* attn_bT= (unsigned short*)(ws + 21 * MB);  // n-major (4096,512)
    unsigned short* low_b  = (unsigned short*)(ws + 25 * MB);
    float* out = (float*)d_out;
    unsigned short* opart = (unsigned short*)d_out;              // 16MB scratch in d_out
    float* lgl = (float*)((char*)d_out + 16 * MB);               // 0.5MB scratch in d_out

    k_pool<<<dim3(72, 512), 256, 0, stream>>>(x, xp, partials, qkvw, projw, temp, wq_b, wp_b);
    k_stats<<<8, 256, 0, stream>>>(partials, gstats);
    k_xr<<<8192, 256, 0, stream>>>(xp, gstats, gnw, gnb, xr_b);
    k_gemmP<<<dim3(32, 12), 256, 0, stream>>>(wq_b, xr_b, qtg, ktg, vtg);
    k_attn<<<dim3(32, 8, 4), 256, 0, stream>>>(qtg, ktg, vtg, opart, lgl);
    k_merge<<<512, 256, 0, stream>>>(opart, lgl, attn_bT);
    k_gemmT<<<dim3(32, 8), 256, 0, stream>>>(wp_b, attn_bT, low_b);
    k_up<<<dim3(64, 512), 256, 0, stream>>>(x, low_b, projb, gamma, out);
}

// Round 14
// 180.488 us; speedup vs baseline: 7.3110x; 1.0641x over previous
//
#include <hip/hip_runtime.h>
#include <hip/hip_bf16.h>

// Pipeline (8 launches):
//  k_pool   : x -> pooled xp + group partials [+ fused wconv]  (plain cached x-load:
//             x stays L3-resident for k_up's second pass)
//  k_stats  : reduce partials -> mean/rstd per group
//  k_xr     : xr = GN_affine(xp) + posenc -> bf16 (512,4096)
//  k_gemmP  : qkv = Wq(1536,512) x xr -> fragment-ordered qtg/ktg/vtg directly
//  k_attn   : flash attn, m==0 softmax, lane-local l, 64-key tiles, dbuf LDS,
//             counted vmcnt, 4 segments (grid 1024 = 4 blocks/CU)
//  k_merge  : sum 4 seg partials -> attn_bT (n-major) bf16
//  k_gemmT  : low = Wp(512,512) x attn_bT^T, 64-row tiles (grid 256)
//  k_up     : out = x + gamma*(bilerp_4x(low)+proj_b); plain x-load (L3 hit),
//             shfl neighbors, NT store (out never re-read)

typedef __attribute__((ext_vector_type(4))) short short4v;
typedef __attribute__((ext_vector_type(8))) short short8v;
typedef __attribute__((ext_vector_type(4))) float f32x4;
typedef __attribute__((ext_vector_type(4))) unsigned int u32x4;

#define MFMA16(a, b, c) __builtin_amdgcn_mfma_f32_16x16x32_bf16(a, b, c, 0, 0, 0)

__device__ __forceinline__ unsigned short bf16r(float f) {
    unsigned int u = __builtin_bit_cast(unsigned int, f);
    u += 0x7fffu + ((u >> 16) & 1u);
    return (unsigned short)(u >> 16);
}
__device__ __forceinline__ float bff(unsigned short s) {
    unsigned int u = ((unsigned int)s) << 16;
    return __builtin_bit_cast(float, u);
}
__device__ __forceinline__ unsigned int fbits(float f) {
    return __builtin_bit_cast(unsigned int, f);
}

typedef const __attribute__((address_space(1))) unsigned int guint;
typedef __attribute__((address_space(3))) unsigned int luint;
__device__ __forceinline__ void gload16(const void* g, void* l) {
    __builtin_amdgcn_global_load_lds((guint*)g, (luint*)l, 16, 0, 0);
}

// ---------------- pool + group partial stats (+ fused weight conversion) ----------------
__global__ __launch_bounds__(256) void k_pool(const float* __restrict__ x,
                                              float* __restrict__ xp,
                                              float* __restrict__ partials,
                                              const float* __restrict__ qkv_w,
                                              const float* __restrict__ proj_w,
                                              const float* __restrict__ temp,
                                              unsigned short* __restrict__ wq_b,
                                              unsigned short* __restrict__ wp_b) {
    int t = threadIdx.x;
    if (blockIdx.x >= 64) {
        int idx = ((blockIdx.x - 64) * 512 + blockIdx.y) * 256 + t;
        const int NQ = 1536 * 512;
        const int NTOT = NQ + 512 * 512;
        if (idx < NQ) {
            int o = idx >> 9;
            float sc = (o < 512) ? temp[o >> 6] * 0.125f * 1.44269504f : 1.0f;
            wq_b[idx] = bf16r(qkv_w[idx] * sc);
        } else if (idx < NTOT) {
            wp_b[idx - NQ] = bf16r(proj_w[idx - NQ]);
        }
        return;
    }
    int hr = blockIdx.x;
    int c  = blockIdx.y;
    int r = t >> 6, wq = t & 63;
    const f32x4* src = (const f32x4*)(x + (size_t)c * 65536 + (size_t)(4 * hr + r) * 256 + 4 * wq);
    f32x4 v = *src;   // plain cached load: keep x L3-resident for k_up
    float s4 = v[0] + v[1] + v[2] + v[3];
    float q4 = v[0] * v[0] + v[1] * v[1] + v[2] * v[2] + v[3] * v[3];

    __shared__ float sm[256];
    __shared__ float wq4[4];
    sm[t] = s4;
    float qq = q4;
#pragma unroll
    for (int off = 1; off < 64; off <<= 1) qq += __shfl_xor(qq, off, 64);
    if ((t & 63) == 0) wq4[t >> 6] = qq;
    __syncthreads();
    if (t < 64) {
        float cs = sm[t] + sm[64 + t] + sm[128 + t] + sm[192 + t];
        xp[(size_t)c * 4096 + hr * 64 + t] = cs * (1.0f / 16.0f);
        float ts = cs;
#pragma unroll
        for (int off = 1; off < 64; off <<= 1) ts += __shfl_xor(ts, off, 64);
        if (t == 0) {
            int g = c >> 6;
            int slot = (c & 63) * 64 + hr;
            partials[(size_t)(g * 4096 + slot) * 2 + 0] = ts;
            partials[(size_t)(g * 4096 + slot) * 2 + 1] = wq4[0] + wq4[1] + wq4[2] + wq4[3];
        }
    }
}

// ---------------- group stats finalize ----------------
__global__ __launch_bounds__(256) void k_stats(const float* __restrict__ partials,
                                               float* __restrict__ gstats) {
    int g = blockIdx.x;
    int t = threadIdx.x;
    float s = 0.f, q = 0.f;
    for (int i = t; i < 4096; i += 256) {
        s += partials[(size_t)(g * 4096 + i) * 2 + 0];
        q += partials[(size_t)(g * 4096 + i) * 2 + 1];
    }
#pragma unroll
    for (int off = 1; off < 64; off <<= 1) {
        s += __shfl_xor(s, off, 64);
        q += __shfl_xor(q, off, 64);
    }
    __shared__ float ss[4], qs[4];
    if ((t & 63) == 0) { ss[t >> 6] = s; qs[t >> 6] = q; }
    __syncthreads();
    if (t == 0) {
        float S = ss[0] + ss[1] + ss[2] + ss[3];
        float Q = qs[0] + qs[1] + qs[2] + qs[3];
        const float inv = 1.0f / 4194304.0f;
        float m = S * inv;
        float var = Q * inv - m * m;
        gstats[2 * g] = m;
        gstats[2 * g + 1] = rsqrtf(var + 1e-5f);
    }
}

// ---------------- GN affine + positional encoding -> bf16 ----------------
__global__ __launch_bounds__(256) void k_xr(const float* __restrict__ xp,
                                            const float* __restrict__ gs,
                                            const float* __restrict__ gw,
                                            const float* __restrict__ gb,
                                            unsigned short* __restrict__ xr) {
    int idx = blockIdx.x * 256 + threadIdx.x;
    int c = idx >> 12, n = idx & 4095;
    int hr = n >> 6, wr = n & 63;
    int g = c >> 6;
    float m = gs[2 * g], rs = gs[2 * g + 1];
    float xn = (xp[idx] - m) * rs * gw[c] + gb[c];
    int i = c >> 2, kind = c & 3;
    float di = expf(-(float)i * 0.07195578415606394f);
    float arg = ((kind < 2) ? (float)hr : (float)wr) * di;
    float pe = 0.01f * ((kind & 1) ? cosf(arg) : sinf(arg));
    xr[idx] = bf16r(xn + pe);
}

// ---------------- QKV GEMM with fused fragment-order epilogue ----------------
__global__ __launch_bounds__(256) void k_gemmP(const unsigned short* __restrict__ A,
                                               const unsigned short* __restrict__ B,
                                               unsigned short* __restrict__ qtg,
                                               unsigned short* __restrict__ ktg,
                                               unsigned short* __restrict__ vtg) {
    __shared__ __align__(16) char smem[33792];
    unsigned short (*As)[36] = (unsigned short(*)[36])smem;
    unsigned short (*Bs)[36] = (unsigned short(*)[36])(smem + 9216);
    unsigned short (*ct)[132] = (unsigned short(*)[132])smem;  // epilogue reuse

    int t = threadIdx.x;
    int w = t >> 6, l = t & 63, l15 = l & 15, lg = l >> 4;
    int wrow = w >> 1, wcol = w & 1;
    int m0 = blockIdx.y * 128, n0 = blockIdx.x * 128;
    f32x4 acc[4][4] = {};

    for (int k0 = 0; k0 < 512; k0 += 32) {
#pragma unroll
        for (int i = 0; i < 4; i++) {
            int idx = t + 256 * i;
            int row = idx >> 3, kc = idx & 7;
            short4v av = *(const short4v*)(A + (size_t)(m0 + row) * 512 + k0 + 4 * kc);
            *(short4v*)&As[row][4 * kc] = av;
        }
#pragma unroll
        for (int i = 0; i < 4; i++) {
            int idx = t + 256 * i;
            int kr = idx >> 5, nc = idx & 31;
            short4v bv = *(const short4v*)(B + (size_t)(k0 + kr) * 4096 + n0 + 4 * nc);
#pragma unroll
            for (int j = 0; j < 4; j++) Bs[4 * nc + j][kr] = (unsigned short)bv[j];
        }
        __syncthreads();

        short8v af[4];
#pragma unroll
        for (int mi = 0; mi < 4; mi++) {
            int ar = wrow * 64 + mi * 16 + l15;
            short4v a0 = *(const short4v*)&As[ar][4 * lg];
            short4v a1 = *(const short4v*)&As[ar][16 + 4 * lg];
            af[mi] = __builtin_shufflevector(a0, a1, 0, 1, 2, 3, 4, 5, 6, 7);
        }
#pragma unroll
        for (int ni = 0; ni < 4; ni++) {
            int bc = wcol * 64 + ni * 16 + l15;
            short4v b0 = *(const short4v*)&Bs[bc][4 * lg];
            short4v b1 = *(const short4v*)&Bs[bc][16 + 4 * lg];
            short8v bf = __builtin_shufflevector(b0, b1, 0, 1, 2, 3, 4, 5, 6, 7);
#pragma unroll
            for (int mi = 0; mi < 4; mi++) acc[mi][ni] = MFMA16(af[mi], bf, acc[mi][ni]);
        }
        __syncthreads();
    }

#pragma unroll
    for (int mi = 0; mi < 4; mi++)
#pragma unroll
        for (int ni = 0; ni < 4; ni++) {
            int ml = wrow * 64 + mi * 16 + 4 * lg;
            int nl = wcol * 64 + ni * 16 + l15;
#pragma unroll
            for (int r = 0; r < 4; r++) ct[ml + r][nl] = bf16r(acc[mi][ni][r]);
        }
    __syncthreads();

    int y = blockIdx.y;
#pragma unroll
    for (int i = 0; i < 8; i++) {
        int gc = t + 256 * i;  // [0, 2048)
        int hg = gc >> 10, rem = gc & 1023;
        unsigned short o[8];
        unsigned short* dst;
        if (y < 4) {  // Q
            int nu_loc = rem >> 8, cidx = rem & 255;
            int s = cidx >> 7, lgc = (cidx >> 5) & 3, col = cidx & 31;
#pragma unroll
            for (int j = 0; j < 4; j++) {
                o[j] = ct[hg * 64 + s * 32 + 4 * lgc + j][nu_loc * 32 + col];
                o[4 + j] = ct[hg * 64 + s * 32 + 16 + 4 * lgc + j][nu_loc * 32 + col];
            }
            int h = y * 2 + hg;
            dst = qtg + ((size_t)(h * 128 + (n0 >> 5) + nu_loc)) * 2048 + cidx * 8;
        } else if (y < 8) {  // K
            int Tloc = rem >> 9, cidx = rem & 511;
            int s = cidx >> 8, lgc = (cidx >> 6) & 3, m64 = cidx & 63;
#pragma unroll
            for (int j = 0; j < 4; j++) {
                o[j] = ct[hg * 64 + s * 32 + 4 * lgc + j][Tloc * 64 + m64];
                o[4 + j] = ct[hg * 64 + s * 32 + 16 + 4 * lgc + j][Tloc * 64 + m64];
            }
            int h = (y - 4) * 2 + hg;
            dst = ktg + ((size_t)(h * 64 + (n0 >> 6) + Tloc)) * 4096 + cidx * 8;
        } else {  // V
            int Tloc = rem >> 9, cidx = rem & 511;
            int mh = cidx >> 8, lgc = (cidx >> 6) & 3, d = cidx & 63;
#pragma unroll
            for (int j = 0; j < 4; j++) {
                o[j] = ct[hg * 64 + d][Tloc * 64 + mh * 32 + 4 * lgc + j];
                o[4 + j] = ct[hg * 64 + d][Tloc * 64 + mh * 32 + 16 + 4 * lgc + j];
            }
            int h = (y - 8) * 2 + hg;
            dst = vtg + ((size_t)(h * 64 + (n0 >> 6) + Tloc)) * 4096 + cidx * 8;
        }
        *(short8v*)dst = *(const short8v*)o;
    }
}

// ---------------- flash attention: 4 segs, dbuf, counted vmcnt ----------------
__global__ __launch_bounds__(256, 5) void k_attn(const unsigned short* __restrict__ qtg,
                                                 const unsigned short* __restrict__ ktg,
                                                 const unsigned short* __restrict__ vtg,
                                                 unsigned short* __restrict__ opart,
                                                 float* __restrict__ lgl) {
    __shared__ __align__(16) unsigned short kbuf[2][4096];
    __shared__ __align__(16) unsigned short vbuf[2][4096];
    int t = threadIdx.x;
    int l = t & 63, l15 = l & 15, lg = l >> 4, w = t >> 6;
    int qt = blockIdx.x, h = blockIdx.y, seg = blockIdx.z;
    int nu = qt * 4 + w;

    const unsigned short* qb = qtg + ((size_t)(h * 128 + nu)) * 2048;
    const unsigned short* kb = ktg + ((size_t)(h * 64 + seg * 16)) * 4096;
    const unsigned short* vb = vtg + ((size_t)(h * 64 + seg * 16)) * 4096;

    short8v qf[2][2];
#pragma unroll
    for (int ng = 0; ng < 2; ng++)
#pragma unroll
        for (int s = 0; s < 2; s++)
            qf[ng][s] = *(const short8v*)(qb + ((s * 4 + lg) * 32 + ng * 16 + l15) * 8);

    f32x4 od[2][4] = {};
    float lsum[2] = {0.f, 0.f};

#define STAGE(kt, b)                                                            \
    {                                                                           \
        gload16(kb + (size_t)(kt) * 4096 + t * 8, &kbuf[b][t * 8]);             \
        gload16(kb + (size_t)(kt) * 4096 + (t + 256) * 8, &kbuf[b][(t + 256) * 8]); \
        gload16(vb + (size_t)(kt) * 4096 + t * 8, &vbuf[b][t * 8]);             \
        gload16(vb + (size_t)(kt) * 4096 + (t + 256) * 8, &vbuf[b][(t + 256) * 8]); \
    }

    STAGE(0, 0);

    int u = 0;
#pragma unroll 1
    for (int j = 0; j < 16; j++) {
        if (j < 15) {
            STAGE(j + 1, u ^ 1);
            asm volatile("s_waitcnt vmcnt(4)" ::: "memory");
        } else {
            asm volatile("s_waitcnt vmcnt(0)" ::: "memory");
        }
        __builtin_amdgcn_s_barrier();
        __builtin_amdgcn_sched_barrier(0);

        const unsigned short* kl = &kbuf[u][0];
        const unsigned short* vl = &vbuf[u][0];

        u32x4 pwA, pwB;
        short8v pb[2][2];
#pragma unroll
        for (int mf = 0; mf < 4; mf++) {
            short8v k0 = *(const short8v*)(kl + ((0 + lg) * 64 + mf * 16 + l15) * 8);
            short8v k1 = *(const short8v*)(kl + ((4 + lg) * 64 + mf * 16 + l15) * 8);
            f32x4 s0 = {}, s1 = {};
            __builtin_amdgcn_s_setprio(1);
            s0 = MFMA16(k0, qf[0][0], s0);
            s0 = MFMA16(k1, qf[0][1], s0);
            s1 = MFMA16(k0, qf[1][0], s1);
            s1 = MFMA16(k1, qf[1][1], s1);
            __builtin_amdgcn_s_setprio(0);
            float p0[4], p1[4];
#pragma unroll
            for (int r = 0; r < 4; r++) {
                p0[r] = __builtin_amdgcn_exp2f(s0[r]);
                p1[r] = __builtin_amdgcn_exp2f(s1[r]);
            }
            lsum[0] += (p0[0] + p0[1]) + (p0[2] + p0[3]);
            lsum[1] += (p1[0] + p1[1]) + (p1[2] + p1[3]);
            if (!(mf & 1)) {
                pwA[0] = __builtin_amdgcn_perm(fbits(p0[1]), fbits(p0[0]), 0x07060302u);
                pwA[1] = __builtin_amdgcn_perm(fbits(p0[3]), fbits(p0[2]), 0x07060302u);
                pwB[0] = __builtin_amdgcn_perm(fbits(p1[1]), fbits(p1[0]), 0x07060302u);
                pwB[1] = __builtin_amdgcn_perm(fbits(p1[3]), fbits(p1[2]), 0x07060302u);
            } else {
                pwA[2] = __builtin_amdgcn_perm(fbits(p0[1]), fbits(p0[0]), 0x07060302u);
                pwA[3] = __builtin_amdgcn_perm(fbits(p0[3]), fbits(p0[2]), 0x07060302u);
                pwB[2] = __builtin_amdgcn_perm(fbits(p1[1]), fbits(p1[0]), 0x07060302u);
                pwB[3] = __builtin_amdgcn_perm(fbits(p1[3]), fbits(p1[2]), 0x07060302u);
                pb[0][mf >> 1] = __builtin_bit_cast(short8v, pwA);
                pb[1][mf >> 1] = __builtin_bit_cast(short8v, pwB);
            }
        }

        __builtin_amdgcn_s_setprio(1);
#pragma unroll
        for (int mh = 0; mh < 2; mh++)
#pragma unroll
            for (int dg = 0; dg < 4; dg++) {
                short8v vf = *(const short8v*)(vl + ((mh * 4 + lg) * 64 + dg * 16 + l15) * 8);
                od[0][dg] = MFMA16(vf, pb[0][mh], od[0][dg]);
                od[1][dg] = MFMA16(vf, pb[1][mh], od[1][dg]);
            }
        __builtin_amdgcn_s_setprio(0);

        __builtin_amdgcn_s_barrier();
        u ^= 1;
    }
#undef STAGE

#pragma unroll
    for (int ng = 0; ng < 2; ng++) {
        lsum[ng] += __shfl_xor(lsum[ng], 16, 64);
        lsum[ng] += __shfl_xor(lsum[ng], 32, 64);
    }

    unsigned short* op = opart + (((size_t)(seg * 8 + h)) * 4096 + nu * 32) * 64;
#pragma unroll
    for (int ng = 0; ng < 2; ng++)
#pragma unroll
        for (int dg = 0; dg < 4; dg++) {
            unsigned short v4[4];
#pragma unroll
            for (int r = 0; r < 4; r++) v4[r] = bf16r(od[ng][dg][r]);
            *(short4v*)(op + (ng * 16 + l15) * 64 + dg * 16 + 4 * lg) = *(const short4v*)v4;
        }
    if (lg == 0) {
#pragma unroll
        for (int ng = 0; ng < 2; ng++)
            lgl[(size_t)(seg * 8 + h) * 4096 + nu * 32 + ng * 16 + l15] = lsum[ng];
    }
}

// ---------------- merge 4 seg partials -> attn_bT (n-major), coalesced ----------------
__global__ __launch_bounds__(256) void k_merge(const unsigned short* __restrict__ opart,
                                               const float* __restrict__ lgl,
                                               unsigned short* __restrict__ attn_bT) {
    int t = threadIdx.x;
    int n = blockIdx.x * 8 + (t >> 5);
    int cid = t & 31;
    int h = cid >> 2, d0 = (cid & 3) * 16;

    float den = 0.f;
    float num[16] = {};
#pragma unroll
    for (int s = 0; s < 4; s++) {
        den += lgl[(size_t)(s * 8 + h) * 4096 + n];
        const unsigned short* row = opart + (((size_t)(s * 8 + h)) * 4096 + n) * 64 + d0;
        short8v a = *(const short8v*)row;
        short8v b = *(const short8v*)(row + 8);
#pragma unroll
        for (int j = 0; j < 8; j++) {
            num[j] += bff((unsigned short)a[j]);
            num[8 + j] += bff((unsigned short)b[j]);
        }
    }
    float inv = 1.0f / den;
    unsigned short res[16];
#pragma unroll
    for (int j = 0; j < 16; j++) res[j] = bf16r(num[j] * inv);
    unsigned short* dst = attn_bT + (size_t)n * 512 + h * 64 + d0;
    *(short8v*)dst = *(const short8v*)&res[0];
    *(short8v*)(dst + 8) = *(const short8v*)&res[8];
}

// ---------------- proj GEMM: C[512,4096] = A[512,512] x BT[4096,512]^T ----------------
__global__ __launch_bounds__(256) void k_gemmT(const unsigned short* __restrict__ A,
                                               const unsigned short* __restrict__ BT,
                                               unsigned short* __restrict__ C) {
    __shared__ unsigned short As[64][36];
    __shared__ unsigned short Bs[128][36];
    int t = threadIdx.x;
    int w = t >> 6, l = t & 63, l15 = l & 15, lg = l >> 4;
    int wrow = w >> 1, wcol = w & 1;
    int m0 = blockIdx.y * 64, n0 = blockIdx.x * 128;
    f32x4 acc[2][4] = {};

    for (int k0 = 0; k0 < 512; k0 += 32) {
#pragma unroll
        for (int i = 0; i < 2; i++) {
            int idx = t + 256 * i;
            int row = idx >> 3, kc = idx & 7;
            short4v av = *(const short4v*)(A + (size_t)(m0 + row) * 512 + k0 + 4 * kc);
            *(short4v*)&As[row][4 * kc] = av;
        }
#pragma unroll
        for (int i = 0; i < 4; i++) {
            int idx = t + 256 * i;
            int row = idx >> 3, kc = idx & 7;
            short4v bv = *(const short4v*)(BT + (size_t)(n0 + row) * 512 + k0 + 4 * kc);
            *(short4v*)&Bs[row][4 * kc] = bv;
        }
        __syncthreads();

        short8v af[2];
#pragma unroll
        for (int mi = 0; mi < 2; mi++) {
            int ar = wrow * 32 + mi * 16 + l15;
            short4v a0 = *(const short4v*)&As[ar][4 * lg];
            short4v a1 = *(const short4v*)&As[ar][16 + 4 * lg];
            af[mi] = __builtin_shufflevector(a0, a1, 0, 1, 2, 3, 4, 5, 6, 7);
        }
#pragma unroll
        for (int ni = 0; ni < 4; ni++) {
            int bc = wcol * 64 + ni * 16 + l15;
            short4v b0 = *(const short4v*)&Bs[bc][4 * lg];
            short4v b1 = *(const short4v*)&Bs[bc][16 + 4 * lg];
            short8v bf = __builtin_shufflevector(b0, b1, 0, 1, 2, 3, 4, 5, 6, 7);
#pragma unroll
            for (int mi = 0; mi < 2; mi++) acc[mi][ni] = MFMA16(af[mi], bf, acc[mi][ni]);
        }
        __syncthreads();
    }
#pragma unroll
    for (int mi = 0; mi < 2; mi++)
#pragma unroll
        for (int ni = 0; ni < 4; ni++) {
            int row = m0 + wrow * 32 + mi * 16 + 4 * lg;
            int col = n0 + wcol * 64 + ni * 16 + l15;
#pragma unroll
            for (int r = 0; r < 4; r++)
                C[(size_t)(row + r) * 4096 + col] = bf16r(acc[mi][ni][r]);
        }
}

// ---------------- bilinear upsample + bias + residual (plain x-load, shfl, NT store) ----------------
__global__ __launch_bounds__(256) void k_up(const float* __restrict__ x,
                                            const unsigned short* __restrict__ low,
                                            const float* __restrict__ proj_b,
                                            const float* __restrict__ gamma,
                                            float* __restrict__ out) {
    int t = threadIdx.x;
    int hs = t >> 6;
    int hh = blockIdx.x * 4 + hs;
    int c = blockIdx.y;
    int a = t & 63;

    int ph = hh & 3, Ah = hh >> 2;
    int y0 = Ah + ((ph < 2) ? -1 : 0);
    float fy = (ph < 2) ? (0.625f + 0.25f * ph) : (0.125f + 0.25f * (ph - 2));
    int y1 = min(y0 + 1, 63); y0 = max(y0, 0);

    const unsigned short* L0 = low + (size_t)c * 4096 + y0 * 64;
    const unsigned short* L1 = low + (size_t)c * 4096 + y1 * 64;
    float gy = 1.f - fy;
    float v0 = gy * bff(L0[a]) + fy * bff(L1[a]);
    float vmu = __shfl_up(v0, 1, 64);
    float vpd = __shfl_down(v0, 1, 64);
    float vm = (a == 0) ? v0 : vmu;
    float vp = (a == 63) ? v0 : vpd;

    float pb = proj_b[c], g = gamma[0];
    size_t idx = (size_t)c * 65536 + (size_t)hh * 256 + a * 4;
    f32x4 xi = *(const f32x4*)(x + idx);   // plain load: x is L3-resident from k_pool
    f32x4 o;
    o[0] = xi[0] + g * (0.375f * vm + 0.625f * v0 + pb);
    o[1] = xi[1] + g * (0.125f * vm + 0.875f * v0 + pb);
    o[2] = xi[2] + g * (0.875f * v0 + 0.125f * vp + pb);
    o[3] = xi[3] + g * (0.625f * v0 + 0.375f * vp + pb);
    __builtin_nontemporal_store(o, (f32x4*)(out + idx));
}

extern "C" void kernel_launch(void* const* d_in, const int* in_sizes, int n_in,
                              void* d_out, int out_size, void* d_ws, size_t ws_size,
                              hipStream_t stream) {
    const float* x     = (const float*)d_in[0];
    const float* gnw   = (const float*)d_in[1];
    const float* gnb   = (const float*)d_in[2];
    const float* qkvw  = (const float*)d_in[3];
    const float* projw = (const float*)d_in[4];
    const float* projb = (const float*)d_in[5];
    const float* gamma = (const float*)d_in[6];
    const float* temp  = (const float*)d_in[7];

    char* ws = (char*)d_ws;
    const size_t MB = 1u << 20;
    float* gstats          = (float*)(ws + 0);
    float* partials        = (float*)(ws + 1024);
    float* xp              = (float*)(ws + 1 * MB);            // dead after k_xr
    unsigned short* qtg    = (unsigned short*)(ws + 1 * MB);   // reuses xp (4MB)
    unsigned short* ktg    = (unsigned short*)(ws + 5 * MB);   // 4MB
    unsigned short* xr_b   = (unsigned short*)(ws + 9 * MB);   // live through gemmP
    unsigned short* vtg    = (unsigned short*)(ws + 13 * MB);  // 4MB
    unsigned short* wq_b   = (unsigned short*)(ws + 17 * MB);
    unsigned short* wp_b   = (unsigned short*)(ws + 19 * MB);
    unsigned short* attn_bT= (unsigned short*)(ws + 21 * MB);  // n-major (4096,512)
    unsigned short* low_b  = (unsigned short*)(ws + 25 * MB);
    float* out = (float*)d_out;
    unsigned short* opart = (unsigned short*)d_out;              // 16MB scratch in d_out
    float* lgl = (float*)((char*)d_out + 16 * MB);               // 0.5MB scratch in d_out

    k_pool<<<dim3(72, 512), 256, 0, stream>>>(x, xp, partials, qkvw, projw, temp, wq_b, wp_b);
    k_stats<<<8, 256, 0, stream>>>(partials, gstats);
    k_xr<<<8192, 256, 0, stream>>>(xp, gstats, gnw, gnb, xr_b);
    k_gemmP<<<dim3(32, 12), 256, 0, stream>>>(wq_b, xr_b, qtg, ktg, vtg);
    k_attn<<<dim3(32, 8, 4), 256, 0, stream>>>(qtg, ktg, vtg, opart, lgl);
    k_merge<<<512, 256, 0, stream>>>(opart, lgl, attn_bT);
    k_gemmT<<<dim3(32, 8), 256, 0, stream>>>(wp_b, attn_bT, low_b);
    k_up<<<dim3(64, 512), 256, 0, stream>>>(x, low_b, projb, gamma, out);
}

// Round 15
// 180.276 us; speedup vs baseline: 7.3196x; 1.0012x over previous
//
#include <hip/hip_runtime.h>
#include <hip/hip_bf16.h>

// Pipeline (8 launches):
//  k_pool   : x -> pooled xp + group partials [+ fused wconv]  (plain cached x-load:
//             x stays L3-resident for k_up's second pass)
//  k_stats  : reduce partials -> mean/rstd per group
//  k_xr     : xr = GN_affine(xp) + posenc -> bf16 (512,4096)
//  k_gemmP  : qkv = Wq(1536,512) x xr -> fragment-ordered qtg/ktg/vtg directly
//  k_attn   : flash attn, m==0 softmax, lane-local l, 64-key tiles, dbuf LDS,
//             counted vmcnt, 4 segments; XCD-bijective block swizzle so all 32
//             qt-blocks sharing one (h,seg) K/V slice land on ONE XCD (L2 reuse)
//  k_merge  : sum 4 seg partials -> attn_bT (n-major) bf16
//  k_gemmT  : low = Wp(512,512) x attn_bT^T, 64-row tiles (grid 256)
//  k_up     : out = x + gamma*(bilerp_4x(low)+proj_b); plain x-load (L3 hit),
//             shfl neighbors, NT store (out never re-read)

typedef __attribute__((ext_vector_type(4))) short short4v;
typedef __attribute__((ext_vector_type(8))) short short8v;
typedef __attribute__((ext_vector_type(4))) float f32x4;
typedef __attribute__((ext_vector_type(4))) unsigned int u32x4;

#define MFMA16(a, b, c) __builtin_amdgcn_mfma_f32_16x16x32_bf16(a, b, c, 0, 0, 0)

__device__ __forceinline__ unsigned short bf16r(float f) {
    unsigned int u = __builtin_bit_cast(unsigned int, f);
    u += 0x7fffu + ((u >> 16) & 1u);
    return (unsigned short)(u >> 16);
}
__device__ __forceinline__ float bff(unsigned short s) {
    unsigned int u = ((unsigned int)s) << 16;
    return __builtin_bit_cast(float, u);
}
__device__ __forceinline__ unsigned int fbits(float f) {
    return __builtin_bit_cast(unsigned int, f);
}

typedef const __attribute__((address_space(1))) unsigned int guint;
typedef __attribute__((address_space(3))) unsigned int luint;
__device__ __forceinline__ void gload16(const void* g, void* l) {
    __builtin_amdgcn_global_load_lds((guint*)g, (luint*)l, 16, 0, 0);
}

// ---------------- pool + group partial stats (+ fused weight conversion) ----------------
__global__ __launch_bounds__(256) void k_pool(const float* __restrict__ x,
                                              float* __restrict__ xp,
                                              float* __restrict__ partials,
                                              const float* __restrict__ qkv_w,
                                              const float* __restrict__ proj_w,
                                              const float* __restrict__ temp,
                                              unsigned short* __restrict__ wq_b,
                                              unsigned short* __restrict__ wp_b) {
    int t = threadIdx.x;
    if (blockIdx.x >= 64) {
        int idx = ((blockIdx.x - 64) * 512 + blockIdx.y) * 256 + t;
        const int NQ = 1536 * 512;
        const int NTOT = NQ + 512 * 512;
        if (idx < NQ) {
            int o = idx >> 9;
            float sc = (o < 512) ? temp[o >> 6] * 0.125f * 1.44269504f : 1.0f;
            wq_b[idx] = bf16r(qkv_w[idx] * sc);
        } else if (idx < NTOT) {
            wp_b[idx - NQ] = bf16r(proj_w[idx - NQ]);
        }
        return;
    }
    int hr = blockIdx.x;
    int c  = blockIdx.y;
    int r = t >> 6, wq = t & 63;
    const f32x4* src = (const f32x4*)(x + (size_t)c * 65536 + (size_t)(4 * hr + r) * 256 + 4 * wq);
    f32x4 v = *src;   // plain cached load: keep x L3-resident for k_up
    float s4 = v[0] + v[1] + v[2] + v[3];
    float q4 = v[0] * v[0] + v[1] * v[1] + v[2] * v[2] + v[3] * v[3];

    __shared__ float sm[256];
    __shared__ float wq4[4];
    sm[t] = s4;
    float qq = q4;
#pragma unroll
    for (int off = 1; off < 64; off <<= 1) qq += __shfl_xor(qq, off, 64);
    if ((t & 63) == 0) wq4[t >> 6] = qq;
    __syncthreads();
    if (t < 64) {
        float cs = sm[t] + sm[64 + t] + sm[128 + t] + sm[192 + t];
        xp[(size_t)c * 4096 + hr * 64 + t] = cs * (1.0f / 16.0f);
        float ts = cs;
#pragma unroll
        for (int off = 1; off < 64; off <<= 1) ts += __shfl_xor(ts, off, 64);
        if (t == 0) {
            int g = c >> 6;
            int slot = (c & 63) * 64 + hr;
            partials[(size_t)(g * 4096 + slot) * 2 + 0] = ts;
            partials[(size_t)(g * 4096 + slot) * 2 + 1] = wq4[0] + wq4[1] + wq4[2] + wq4[3];
        }
    }
}

// ---------------- group stats finalize ----------------
__global__ __launch_bounds__(256) void k_stats(const float* __restrict__ partials,
                                               float* __restrict__ gstats) {
    int g = blockIdx.x;
    int t = threadIdx.x;
    float s = 0.f, q = 0.f;
    for (int i = t; i < 4096; i += 256) {
        s += partials[(size_t)(g * 4096 + i) * 2 + 0];
        q += partials[(size_t)(g * 4096 + i) * 2 + 1];
    }
#pragma unroll
    for (int off = 1; off < 64; off <<= 1) {
        s += __shfl_xor(s, off, 64);
        q += __shfl_xor(q, off, 64);
    }
    __shared__ float ss[4], qs[4];
    if ((t & 63) == 0) { ss[t >> 6] = s; qs[t >> 6] = q; }
    __syncthreads();
    if (t == 0) {
        float S = ss[0] + ss[1] + ss[2] + ss[3];
        float Q = qs[0] + qs[1] + qs[2] + qs[3];
        const float inv = 1.0f / 4194304.0f;
        float m = S * inv;
        float var = Q * inv - m * m;
        gstats[2 * g] = m;
        gstats[2 * g + 1] = rsqrtf(var + 1e-5f);
    }
}

// ---------------- GN affine + positional encoding -> bf16 ----------------
__global__ __launch_bounds__(256) void k_xr(const float* __restrict__ xp,
                                            const float* __restrict__ gs,
                                            const float* __restrict__ gw,
                                            const float* __restrict__ gb,
                                            unsigned short* __restrict__ xr) {
    int idx = blockIdx.x * 256 + threadIdx.x;
    int c = idx >> 12, n = idx & 4095;
    int hr = n >> 6, wr = n & 63;
    int g = c >> 6;
    float m = gs[2 * g], rs = gs[2 * g + 1];
    float xn = (xp[idx] - m) * rs * gw[c] + gb[c];
    int i = c >> 2, kind = c & 3;
    float di = expf(-(float)i * 0.07195578415606394f);
    float arg = ((kind < 2) ? (float)hr : (float)wr) * di;
    float pe = 0.01f * ((kind & 1) ? cosf(arg) : sinf(arg));
    xr[idx] = bf16r(xn + pe);
}

// ---------------- QKV GEMM with fused fragment-order epilogue ----------------
__global__ __launch_bounds__(256) void k_gemmP(const unsigned short* __restrict__ A,
                                               const unsigned short* __restrict__ B,
                                               unsigned short* __restrict__ qtg,
                                               unsigned short* __restrict__ ktg,
                                               unsigned short* __restrict__ vtg) {
    __shared__ __align__(16) char smem[33792];
    unsigned short (*As)[36] = (unsigned short(*)[36])smem;
    unsigned short (*Bs)[36] = (unsigned short(*)[36])(smem + 9216);
    unsigned short (*ct)[132] = (unsigned short(*)[132])smem;  // epilogue reuse

    int t = threadIdx.x;
    int w = t >> 6, l = t & 63, l15 = l & 15, lg = l >> 4;
    int wrow = w >> 1, wcol = w & 1;
    int m0 = blockIdx.y * 128, n0 = blockIdx.x * 128;
    f32x4 acc[4][4] = {};

    for (int k0 = 0; k0 < 512; k0 += 32) {
#pragma unroll
        for (int i = 0; i < 4; i++) {
            int idx = t + 256 * i;
            int row = idx >> 3, kc = idx & 7;
            short4v av = *(const short4v*)(A + (size_t)(m0 + row) * 512 + k0 + 4 * kc);
            *(short4v*)&As[row][4 * kc] = av;
        }
#pragma unroll
        for (int i = 0; i < 4; i++) {
            int idx = t + 256 * i;
            int kr = idx >> 5, nc = idx & 31;
            short4v bv = *(const short4v*)(B + (size_t)(k0 + kr) * 4096 + n0 + 4 * nc);
#pragma unroll
            for (int j = 0; j < 4; j++) Bs[4 * nc + j][kr] = (unsigned short)bv[j];
        }
        __syncthreads();

        short8v af[4];
#pragma unroll
        for (int mi = 0; mi < 4; mi++) {
            int ar = wrow * 64 + mi * 16 + l15;
            short4v a0 = *(const short4v*)&As[ar][4 * lg];
            short4v a1 = *(const short4v*)&As[ar][16 + 4 * lg];
            af[mi] = __builtin_shufflevector(a0, a1, 0, 1, 2, 3, 4, 5, 6, 7);
        }
#pragma unroll
        for (int ni = 0; ni < 4; ni++) {
            int bc = wcol * 64 + ni * 16 + l15;
            short4v b0 = *(const short4v*)&Bs[bc][4 * lg];
            short4v b1 = *(const short4v*)&Bs[bc][16 + 4 * lg];
            short8v bf = __builtin_shufflevector(b0, b1, 0, 1, 2, 3, 4, 5, 6, 7);
#pragma unroll
            for (int mi = 0; mi < 4; mi++) acc[mi][ni] = MFMA16(af[mi], bf, acc[mi][ni]);
        }
        __syncthreads();
    }

#pragma unroll
    for (int mi = 0; mi < 4; mi++)
#pragma unroll
        for (int ni = 0; ni < 4; ni++) {
            int ml = wrow * 64 + mi * 16 + 4 * lg;
            int nl = wcol * 64 + ni * 16 + l15;
#pragma unroll
            for (int r = 0; r < 4; r++) ct[ml + r][nl] = bf16r(acc[mi][ni][r]);
        }
    __syncthreads();

    int y = blockIdx.y;
#pragma unroll
    for (int i = 0; i < 8; i++) {
        int gc = t + 256 * i;  // [0, 2048)
        int hg = gc >> 10, rem = gc & 1023;
        unsigned short o[8];
        unsigned short* dst;
        if (y < 4) {  // Q
            int nu_loc = rem >> 8, cidx = rem & 255;
            int s = cidx >> 7, lgc = (cidx >> 5) & 3, col = cidx & 31;
#pragma unroll
            for (int j = 0; j < 4; j++) {
                o[j] = ct[hg * 64 + s * 32 + 4 * lgc + j][nu_loc * 32 + col];
                o[4 + j] = ct[hg * 64 + s * 32 + 16 + 4 * lgc + j][nu_loc * 32 + col];
            }
            int h = y * 2 + hg;
            dst = qtg + ((size_t)(h * 128 + (n0 >> 5) + nu_loc)) * 2048 + cidx * 8;
        } else if (y < 8) {  // K
            int Tloc = rem >> 9, cidx = rem & 511;
            int s = cidx >> 8, lgc = (cidx >> 6) & 3, m64 = cidx & 63;
#pragma unroll
            for (int j = 0; j < 4; j++) {
                o[j] = ct[hg * 64 + s * 32 + 4 * lgc + j][Tloc * 64 + m64];
                o[4 + j] = ct[hg * 64 + s * 32 + 16 + 4 * lgc + j][Tloc * 64 + m64];
            }
            int h = (y - 4) * 2 + hg;
            dst = ktg + ((size_t)(h * 64 + (n0 >> 6) + Tloc)) * 4096 + cidx * 8;
        } else {  // V
            int Tloc = rem >> 9, cidx = rem & 511;
            int mh = cidx >> 8, lgc = (cidx >> 6) & 3, d = cidx & 63;
#pragma unroll
            for (int j = 0; j < 4; j++) {
                o[j] = ct[hg * 64 + d][Tloc * 64 + mh * 32 + 4 * lgc + j];
                o[4 + j] = ct[hg * 64 + d][Tloc * 64 + mh * 32 + 16 + 4 * lgc + j];
            }
            int h = (y - 8) * 2 + hg;
            dst = vtg + ((size_t)(h * 64 + (n0 >> 6) + Tloc)) * 4096 + cidx * 8;
        }
        *(short8v*)dst = *(const short8v*)o;
    }
}

// ---------------- flash attention: 4 segs, dbuf, counted vmcnt, XCD swizzle ----------------
// grid 1024 blocks (flat). Bijective remap work=(fid&7)*128+(fid>>3): each XCD gets
// 128 consecutive work items = 4 complete (h,seg) groups, so each 256KB K/V slice is
// fetched into exactly one XCD's L2 and reused by its 32 qt-blocks.
__global__ __launch_bounds__(256, 5) void k_attn(const unsigned short* __restrict__ qtg,
                                                 const unsigned short* __restrict__ ktg,
                                                 const unsigned short* __restrict__ vtg,
                                                 unsigned short* __restrict__ opart,
                                                 float* __restrict__ lgl) {
    __shared__ __align__(16) unsigned short kbuf[2][4096];
    __shared__ __align__(16) unsigned short vbuf[2][4096];
    int t = threadIdx.x;
    int l = t & 63, l15 = l & 15, lg = l >> 4, w = t >> 6;
    int fid = blockIdx.x;
    int work = (fid & 7) * 128 + (fid >> 3);
    int qt = work & 31, h = (work >> 5) & 7, seg = work >> 8;
    int nu = qt * 4 + w;

    const unsigned short* qb = qtg + ((size_t)(h * 128 + nu)) * 2048;
    const unsigned short* kb = ktg + ((size_t)(h * 64 + seg * 16)) * 4096;
    const unsigned short* vb = vtg + ((size_t)(h * 64 + seg * 16)) * 4096;

    short8v qf[2][2];
#pragma unroll
    for (int ng = 0; ng < 2; ng++)
#pragma unroll
        for (int s = 0; s < 2; s++)
            qf[ng][s] = *(const short8v*)(qb + ((s * 4 + lg) * 32 + ng * 16 + l15) * 8);

    f32x4 od[2][4] = {};
    float lsum[2] = {0.f, 0.f};

#define STAGE(kt, b)                                                            \
    {                                                                           \
        gload16(kb + (size_t)(kt) * 4096 + t * 8, &kbuf[b][t * 8]);             \
        gload16(kb + (size_t)(kt) * 4096 + (t + 256) * 8, &kbuf[b][(t + 256) * 8]); \
        gload16(vb + (size_t)(kt) * 4096 + t * 8, &vbuf[b][t * 8]);             \
        gload16(vb + (size_t)(kt) * 4096 + (t + 256) * 8, &vbuf[b][(t + 256) * 8]); \
    }

    STAGE(0, 0);

    int u = 0;
#pragma unroll 1
    for (int j = 0; j < 16; j++) {
        if (j < 15) {
            STAGE(j + 1, u ^ 1);
            asm volatile("s_waitcnt vmcnt(4)" ::: "memory");
        } else {
            asm volatile("s_waitcnt vmcnt(0)" ::: "memory");
        }
        __builtin_amdgcn_s_barrier();
        __builtin_amdgcn_sched_barrier(0);

        const unsigned short* kl = &kbuf[u][0];
        const unsigned short* vl = &vbuf[u][0];

        u32x4 pwA, pwB;
        short8v pb[2][2];
#pragma unroll
        for (int mf = 0; mf < 4; mf++) {
            short8v k0 = *(const short8v*)(kl + ((0 + lg) * 64 + mf * 16 + l15) * 8);
            short8v k1 = *(const short8v*)(kl + ((4 + lg) * 64 + mf * 16 + l15) * 8);
            f32x4 s0 = {}, s1 = {};
            __builtin_amdgcn_s_setprio(1);
            s0 = MFMA16(k0, qf[0][0], s0);
            s0 = MFMA16(k1, qf[0][1], s0);
            s1 = MFMA16(k0, qf[1][0], s1);
            s1 = MFMA16(k1, qf[1][1], s1);
            __builtin_amdgcn_s_setprio(0);
            float p0[4], p1[4];
#pragma unroll
            for (int r = 0; r < 4; r++) {
                p0[r] = __builtin_amdgcn_exp2f(s0[r]);
                p1[r] = __builtin_amdgcn_exp2f(s1[r]);
            }
            lsum[0] += (p0[0] + p0[1]) + (p0[2] + p0[3]);
            lsum[1] += (p1[0] + p1[1]) + (p1[2] + p1[3]);
            if (!(mf & 1)) {
                pwA[0] = __builtin_amdgcn_perm(fbits(p0[1]), fbits(p0[0]), 0x07060302u);
                pwA[1] = __builtin_amdgcn_perm(fbits(p0[3]), fbits(p0[2]), 0x07060302u);
                pwB[0] = __builtin_amdgcn_perm(fbits(p1[1]), fbits(p1[0]), 0x07060302u);
                pwB[1] = __builtin_amdgcn_perm(fbits(p1[3]), fbits(p1[2]), 0x07060302u);
            } else {
                pwA[2] = __builtin_amdgcn_perm(fbits(p0[1]), fbits(p0[0]), 0x07060302u);
                pwA[3] = __builtin_amdgcn_perm(fbits(p0[3]), fbits(p0[2]), 0x07060302u);
                pwB[2] = __builtin_amdgcn_perm(fbits(p1[1]), fbits(p1[0]), 0x07060302u);
                pwB[3] = __builtin_amdgcn_perm(fbits(p1[3]), fbits(p1[2]), 0x07060302u);
                pb[0][mf >> 1] = __builtin_bit_cast(short8v, pwA);
                pb[1][mf >> 1] = __builtin_bit_cast(short8v, pwB);
            }
        }

        __builtin_amdgcn_s_setprio(1);
#pragma unroll
        for (int mh = 0; mh < 2; mh++)
#pragma unroll
            for (int dg = 0; dg < 4; dg++) {
                short8v vf = *(const short8v*)(vl + ((mh * 4 + lg) * 64 + dg * 16 + l15) * 8);
                od[0][dg] = MFMA16(vf, pb[0][mh], od[0][dg]);
                od[1][dg] = MFMA16(vf, pb[1][mh], od[1][dg]);
            }
        __builtin_amdgcn_s_setprio(0);

        __builtin_amdgcn_s_barrier();
        u ^= 1;
    }
#undef STAGE

#pragma unroll
    for (int ng = 0; ng < 2; ng++) {
        lsum[ng] += __shfl_xor(lsum[ng], 16, 64);
        lsum[ng] += __shfl_xor(lsum[ng], 32, 64);
    }

    unsigned short* op = opart + (((size_t)(seg * 8 + h)) * 4096 + nu * 32) * 64;
#pragma unroll
    for (int ng = 0; ng < 2; ng++)
#pragma unroll
        for (int dg = 0; dg < 4; dg++) {
            unsigned short v4[4];
#pragma unroll
            for (int r = 0; r < 4; r++) v4[r] = bf16r(od[ng][dg][r]);
            *(short4v*)(op + (ng * 16 + l15) * 64 + dg * 16 + 4 * lg) = *(const short4v*)v4;
        }
    if (lg == 0) {
#pragma unroll
        for (int ng = 0; ng < 2; ng++)
            lgl[(size_t)(seg * 8 + h) * 4096 + nu * 32 + ng * 16 + l15] = lsum[ng];
    }
}

// ---------------- merge 4 seg partials -> attn_bT (n-major), coalesced ----------------
__global__ __launch_bounds__(256) void k_merge(const unsigned short* __restrict__ opart,
                                               const float* __restrict__ lgl,
                                               unsigned short* __restrict__ attn_bT) {
    int t = threadIdx.x;
    int n = blockIdx.x * 8 + (t >> 5);
    int cid = t & 31;
    int h = cid >> 2, d0 = (cid & 3) * 16;

    float den = 0.f;
    float num[16] = {};
#pragma unroll
    for (int s = 0; s < 4; s++) {
        den += lgl[(size_t)(s * 8 + h) * 4096 + n];
        const unsigned short* row = opart + (((size_t)(s * 8 + h)) * 4096 + n) * 64 + d0;
        short8v a = *(const short8v*)row;
        short8v b = *(const short8v*)(row + 8);
#pragma unroll
        for (int j = 0; j < 8; j++) {
            num[j] += bff((unsigned short)a[j]);
            num[8 + j] += bff((unsigned short)b[j]);
        }
    }
    float inv = 1.0f / den;
    unsigned short res[16];
#pragma unroll
    for (int j = 0; j < 16; j++) res[j] = bf16r(num[j] * inv);
    unsigned short* dst = attn_bT + (size_t)n * 512 + h * 64 + d0;
    *(short8v*)dst = *(const short8v*)&res[0];
    *(short8v*)(dst + 8) = *(const short8v*)&res[8];
}

// ---------------- proj GEMM: C[512,4096] = A[512,512] x BT[4096,512]^T ----------------
__global__ __launch_bounds__(256) void k_gemmT(const unsigned short* __restrict__ A,
                                               const unsigned short* __restrict__ BT,
                                               unsigned short* __restrict__ C) {
    __shared__ unsigned short As[64][36];
    __shared__ unsigned short Bs[128][36];
    int t = threadIdx.x;
    int w = t >> 6, l = t & 63, l15 = l & 15, lg = l >> 4;
    int wrow = w >> 1, wcol = w & 1;
    int m0 = blockIdx.y * 64, n0 = blockIdx.x * 128;
    f32x4 acc[2][4] = {};

    for (int k0 = 0; k0 < 512; k0 += 32) {
#pragma unroll
        for (int i = 0; i < 2; i++) {
            int idx = t + 256 * i;
            int row = idx >> 3, kc = idx & 7;
            short4v av = *(const short4v*)(A + (size_t)(m0 + row) * 512 + k0 + 4 * kc);
            *(short4v*)&As[row][4 * kc] = av;
        }
#pragma unroll
        for (int i = 0; i < 4; i++) {
            int idx = t + 256 * i;
            int row = idx >> 3, kc = idx & 7;
            short4v bv = *(const short4v*)(BT + (size_t)(n0 + row) * 512 + k0 + 4 * kc);
            *(short4v*)&Bs[row][4 * kc] = bv;
        }
        __syncthreads();

        short8v af[2];
#pragma unroll
        for (int mi = 0; mi < 2; mi++) {
            int ar = wrow * 32 + mi * 16 + l15;
            short4v a0 = *(const short4v*)&As[ar][4 * lg];
            short4v a1 = *(const short4v*)&As[ar][16 + 4 * lg];
            af[mi] = __builtin_shufflevector(a0, a1, 0, 1, 2, 3, 4, 5, 6, 7);
        }
#pragma unroll
        for (int ni = 0; ni < 4; ni++) {
            int bc = wcol * 64 + ni * 16 + l15;
            short4v b0 = *(const short4v*)&Bs[bc][4 * lg];
            short4v b1 = *(const short4v*)&Bs[bc][16 + 4 * lg];
            short8v bf = __builtin_shufflevector(b0, b1, 0, 1, 2, 3, 4, 5, 6, 7);
#pragma unroll
            for (int mi = 0; mi < 2; mi++) acc[mi][ni] = MFMA16(af[mi], bf, acc[mi][ni]);
        }
        __syncthreads();
    }
#pragma unroll
    for (int mi = 0; mi < 2; mi++)
#pragma unroll
        for (int ni = 0; ni < 4; ni++) {
            int row = m0 + wrow * 32 + mi * 16 + 4 * lg;
            int col = n0 + wcol * 64 + ni * 16 + l15;
#pragma unroll
            for (int r = 0; r < 4; r++)
                C[(size_t)(row + r) * 4096 + col] = bf16r(acc[mi][ni][r]);
        }
}

// ---------------- bilinear upsample + bias + residual (plain x-load, shfl, NT store) ----------------
__global__ __launch_bounds__(256) void k_up(const float* __restrict__ x,
                                            const unsigned short* __restrict__ low,
                                            const float* __restrict__ proj_b,
                                            const float* __restrict__ gamma,
                                            float* __restrict__ out) {
    int t = threadIdx.x;
    int hs = t >> 6;
    int hh = blockIdx.x * 4 + hs;
    int c = blockIdx.y;
    int a = t & 63;

    int ph = hh & 3, Ah = hh >> 2;
    int y0 = Ah + ((ph < 2) ? -1 : 0);
    float fy = (ph < 2) ? (0.625f + 0.25f * ph) : (0.125f + 0.25f * (ph - 2));
    int y1 = min(y0 + 1, 63); y0 = max(y0, 0);

    const unsigned short* L0 = low + (size_t)c * 4096 + y0 * 64;
    const unsigned short* L1 = low + (size_t)c * 4096 + y1 * 64;
    float gy = 1.f - fy;
    float v0 = gy * bff(L0[a]) + fy * bff(L1[a]);
    float vmu = __shfl_up(v0, 1, 64);
    float vpd = __shfl_down(v0, 1, 64);
    float vm = (a == 0) ? v0 : vmu;
    float vp = (a == 63) ? v0 : vpd;

    float pb = proj_b[c], g = gamma[0];
    size_t idx = (size_t)c * 65536 + (size_t)hh * 256 + a * 4;
    f32x4 xi = *(const f32x4*)(x + idx);   // plain load: x is L3-resident from k_pool
    f32x4 o;
    o[0] = xi[0] + g * (0.375f * vm + 0.625f * v0 + pb);
    o[1] = xi[1] + g * (0.125f * vm + 0.875f * v0 + pb);
    o[2] = xi[2] + g * (0.875f * v0 + 0.125f * vp + pb);
    o[3] = xi[3] + g * (0.625f * v0 + 0.375f * vp + pb);
    __builtin_nontemporal_store(o, (f32x4*)(out + idx));
}

extern "C" void kernel_launch(void* const* d_in, const int* in_sizes, int n_in,
                              void* d_out, int out_size, void* d_ws, size_t ws_size,
                              hipStream_t stream) {
    const float* x     = (const float*)d_in[0];
    const float* gnw   = (const float*)d_in[1];
    const float* gnb   = (const float*)d_in[2];
    const float* qkvw  = (const float*)d_in[3];
    const float* projw = (const float*)d_in[4];
    const float* projb = (const float*)d_in[5];
    const float* gamma = (const float*)d_in[6];
    const float* temp  = (const float*)d_in[7];

    char* ws = (char*)d_ws;
    const size_t MB = 1u << 20;
    float* gstats          = (float*)(ws + 0);
    float* partials        = (float*)(ws + 1024);
    float* xp              = (float*)(ws + 1 * MB);            // dead after k_xr
    unsigned short* qtg    = (unsigned short*)(ws + 1 * MB);   // reuses xp (4MB)
    unsigned short* ktg    = (unsigned short*)(ws + 5 * MB);   // 4MB
    unsigned short* xr_b   = (unsigned short*)(ws + 9 * MB);   // live through gemmP
    unsigned short* vtg    = (unsigned short*)(ws + 13 * MB);  // 4MB
    unsigned short* wq_b   = (unsigned short*)(ws + 17 * MB);
    unsigned short* wp_b   = (unsigned short*)(ws + 19 * MB);
    unsigned short* attn_bT= (unsigned short*)(ws + 21 * MB);  // n-major (4096,512)
    unsigned short* low_b  = (unsigned short*)(ws + 25 * MB);
    float* out = (float*)d_out;
    unsigned short* opart = (unsigned short*)d_out;              // 16MB scratch in d_out
    float* lgl = (float*)((char*)d_out + 16 * MB);               // 0.5MB scratch in d_out

    k_pool<<<dim3(72, 512), 256, 0, stream>>>(x, xp, partials, qkvw, projw, temp, wq_b, wp_b);
    k_stats<<<8, 256, 0, stream>>>(partials, gstats);
    k_xr<<<8192, 256, 0, stream>>>(xp, gstats, gnw, gnb, xr_b);
    k_gemmP<<<dim3(32, 12), 256, 0, stream>>>(wq_b, xr_b, qtg, ktg, vtg);
    k_attn<<<1024, 256, 0, stream>>>(qtg, ktg, vtg, opart, lgl);
    k_merge<<<512, 256, 0, stream>>>(opart, lgl, attn_bT);
    k_gemmT<<<dim3(32, 8), 256, 0, stream>>>(wp_b, attn_bT, low_b);
    k_up<<<dim3(64, 512), 256, 0, stream>>>(x, low_b, projb, gamma, out);
}